// Round 1
// baseline (5033.422 us; speedup 1.0000x reference)
//
#include <hip/hip_runtime.h>

#define NUM_E 100000
#define NUM_M 200000
#define DIM   128
#define HID   256
#define NG    64
#define TITER 3

__device__ __forceinline__ float sigmoidf_(float v) {
  return 1.f / (1.f + __expf(-v));
}
__device__ __forceinline__ float tanhf_(float u) {
  u = fminf(fmaxf(u, -15.f), 15.f);
  float ex = __expf(-2.f * u);
  return (1.f - ex) / (1.f + ex);
}
__device__ __forceinline__ float relu_(float v) { return fmaxf(v, 0.f); }

// ---------------- zero ----------------
__global__ void zero_kernel(float4* __restrict__ p, int n4) {
  int i = blockIdx.x * blockDim.x + threadIdx.x;
  if (i < n4) p[i] = make_float4(0.f, 0.f, 0.f, 0.f);
}

// ---------------- message MLP + scatter ----------------
// grid = NUM_M/64, block = 256
__global__ __launch_bounds__(256) void msg_kernel(
    const float* __restrict__ ls,
    const int* __restrict__ first, const int* __restrict__ second,
    const float* __restrict__ W1, const float* __restrict__ b1,
    const float* __restrict__ W2, const float* __restrict__ b2,
    float* __restrict__ edges)
{
  constexpr int TM = 64;
  constexpr int XST = 260;            // 256 + 4 pad -> only 2-way LDS aliasing (free)
  __shared__ __align__(16) float Xs[TM * XST];
  __shared__ int fidx[TM], sidx[TM];

  const int tid = threadIdx.x;
  const int m0 = blockIdx.x * TM;

  if (tid < TM) fidx[tid] = first[m0 + tid];
  else if (tid < 2 * TM) sidx[tid - TM] = second[m0 + tid - TM];
  __syncthreads();

  // stage gathered concat([ls[first], ls[second]]) tile: [64, 256]
  for (int p = tid; p < TM * 64; p += 256) {
    int row = p >> 6;
    int col = (p & 63) * 4;
    const float* src = (col < DIM) ? (ls + (size_t)fidx[row] * DIM + col)
                                   : (ls + (size_t)sidx[row] * DIM + (col - DIM));
    *(float4*)&Xs[row * XST + col] = *(const float4*)src;
  }
  __syncthreads();

  const int ty = tid >> 4, tx = tid & 15;
  const int r0 = ty * 4;

  // ---- layer 1: [64,256] @ W1[256,256], micro-tile 4 rows x 16 cols ----
  float acc[4][16];
  #pragma unroll
  for (int i = 0; i < 4; ++i)
    #pragma unroll
    for (int j = 0; j < 16; ++j) acc[i][j] = 0.f;

  const float4* W1v = (const float4*)W1;   // row k = 64 float4
  #pragma unroll 2
  for (int k = 0; k < 2 * DIM; ++k) {
    float a0 = Xs[(r0 + 0) * XST + k];
    float a1 = Xs[(r0 + 1) * XST + k];
    float a2 = Xs[(r0 + 2) * XST + k];
    float a3 = Xs[(r0 + 3) * XST + k];
    #pragma unroll
    for (int j = 0; j < 4; ++j) {
      float4 b = W1v[k * (HID / 4) + tx + 16 * j];
      int jb = j * 4;
      acc[0][jb+0] += a0*b.x; acc[0][jb+1] += a0*b.y; acc[0][jb+2] += a0*b.z; acc[0][jb+3] += a0*b.w;
      acc[1][jb+0] += a1*b.x; acc[1][jb+1] += a1*b.y; acc[1][jb+2] += a1*b.z; acc[1][jb+3] += a1*b.w;
      acc[2][jb+0] += a2*b.x; acc[2][jb+1] += a2*b.y; acc[2][jb+2] += a2*b.z; acc[2][jb+3] += a2*b.w;
      acc[3][jb+0] += a3*b.x; acc[3][jb+1] += a3*b.y; acc[3][jb+2] += a3*b.z; acc[3][jb+3] += a3*b.w;
    }
  }

  float4 b1v[4];
  #pragma unroll
  for (int j = 0; j < 4; ++j) b1v[j] = ((const float4*)b1)[tx + 16 * j];

  __syncthreads();
  // relu + bias, write h1 back into Xs (same [64,256] footprint)
  #pragma unroll
  for (int i = 0; i < 4; ++i) {
    #pragma unroll
    for (int j = 0; j < 4; ++j) {
      float4 v;
      v.x = relu_(acc[i][j*4+0] + b1v[j].x);
      v.y = relu_(acc[i][j*4+1] + b1v[j].y);
      v.z = relu_(acc[i][j*4+2] + b1v[j].z);
      v.w = relu_(acc[i][j*4+3] + b1v[j].w);
      *(float4*)&Xs[(r0 + i) * XST + tx * 4 + 64 * j] = v;
    }
  }
  __syncthreads();

  // ---- layer 2: [64,256] @ W2[256,128], micro-tile 4 rows x 8 cols ----
  float acc2[4][8];
  #pragma unroll
  for (int i = 0; i < 4; ++i)
    #pragma unroll
    for (int j = 0; j < 8; ++j) acc2[i][j] = 0.f;

  const float4* W2v = (const float4*)W2;   // row k = 32 float4
  #pragma unroll 2
  for (int k = 0; k < HID; ++k) {
    float a0 = Xs[(r0 + 0) * XST + k];
    float a1 = Xs[(r0 + 1) * XST + k];
    float a2 = Xs[(r0 + 2) * XST + k];
    float a3 = Xs[(r0 + 3) * XST + k];
    #pragma unroll
    for (int j = 0; j < 2; ++j) {
      float4 b = W2v[k * (DIM / 4) + tx + 16 * j];
      int jb = j * 4;
      acc2[0][jb+0] += a0*b.x; acc2[0][jb+1] += a0*b.y; acc2[0][jb+2] += a0*b.z; acc2[0][jb+3] += a0*b.w;
      acc2[1][jb+0] += a1*b.x; acc2[1][jb+1] += a1*b.y; acc2[1][jb+2] += a1*b.z; acc2[1][jb+3] += a1*b.w;
      acc2[2][jb+0] += a2*b.x; acc2[2][jb+1] += a2*b.y; acc2[2][jb+2] += a2*b.z; acc2[2][jb+3] += a2*b.w;
      acc2[3][jb+0] += a3*b.x; acc2[3][jb+1] += a3*b.y; acc2[3][jb+2] += a3*b.z; acc2[3][jb+3] += a3*b.w;
    }
  }

  float4 b2v[2];
  #pragma unroll
  for (int j = 0; j < 2; ++j) b2v[j] = ((const float4*)b2)[tx + 16 * j];

  // relu + bias, scatter-add into edges[second]
  #pragma unroll
  for (int i = 0; i < 4; ++i) {
    float* dst = edges + (size_t)sidx[r0 + i] * DIM;
    #pragma unroll
    for (int j = 0; j < 2; ++j) {
      int c = tx * 4 + 64 * j;
      atomicAdd(&dst[c + 0], relu_(acc2[i][j*4+0] + b2v[j].x));
      atomicAdd(&dst[c + 1], relu_(acc2[i][j*4+1] + b2v[j].y));
      atomicAdd(&dst[c + 2], relu_(acc2[i][j*4+2] + b2v[j].z));
      atomicAdd(&dst[c + 3], relu_(acc2[i][j*4+3] + b2v[j].w));
    }
  }
}

// ---------------- GRU ----------------
// grid = NUM_E/32, block = 256; updates h in place
__global__ __launch_bounds__(256) void gru_kernel(
    const float* __restrict__ x,     // edges_inputs [E,128]
    float* __restrict__ h,           // link_state [E,128], in-place
    const float* __restrict__ gk, const float* __restrict__ gr,
    const float* __restrict__ gb)
{
  constexpr int TE = 32;
  constexpr int ST = 132;            // 128 + 4 pad
  __shared__ __align__(16) float Xs[TE * ST];
  __shared__ __align__(16) float Hs[TE * ST];

  const int tid = threadIdx.x;
  const int e0 = blockIdx.x * TE;

  for (int p = tid; p < TE * 32; p += 256) {
    int row = p >> 5;
    int col = (p & 31) * 4;
    *(float4*)&Xs[row * ST + col] = *(const float4*)(x + (size_t)(e0 + row) * DIM + col);
    *(float4*)&Hs[row * ST + col] = *(const float4*)(h + (size_t)(e0 + row) * DIM + col);
  }
  __syncthreads();

  const int ty = tid >> 4, tx = tid & 15;
  const int r0 = ty * 2;

  float xz[2][8] = {}, xr_[2][8] = {}, xh[2][8] = {};
  float hz[2][8] = {}, hr[2][8] = {}, hh[2][8] = {};

  const float4* gkv = (const float4*)gk;  // row k = 96 float4 (z|r|h each 32)
  const float4* grv = (const float4*)gr;

  #pragma unroll 1
  for (int k = 0; k < DIM; ++k) {
    float ax0 = Xs[(r0 + 0) * ST + k];
    float ax1 = Xs[(r0 + 1) * ST + k];
    float ah0 = Hs[(r0 + 0) * ST + k];
    float ah1 = Hs[(r0 + 1) * ST + k];
    #pragma unroll
    for (int j = 0; j < 2; ++j) {
      int c4 = tx + 16 * j;
      int jb = j * 4;
      float4 bz = gkv[k * 96 + c4];
      float4 br = gkv[k * 96 + 32 + c4];
      float4 bh = gkv[k * 96 + 64 + c4];
      float4 cz = grv[k * 96 + c4];
      float4 cr = grv[k * 96 + 32 + c4];
      float4 ch = grv[k * 96 + 64 + c4];
      xz[0][jb+0]+=ax0*bz.x; xz[0][jb+1]+=ax0*bz.y; xz[0][jb+2]+=ax0*bz.z; xz[0][jb+3]+=ax0*bz.w;
      xz[1][jb+0]+=ax1*bz.x; xz[1][jb+1]+=ax1*bz.y; xz[1][jb+2]+=ax1*bz.z; xz[1][jb+3]+=ax1*bz.w;
      xr_[0][jb+0]+=ax0*br.x; xr_[0][jb+1]+=ax0*br.y; xr_[0][jb+2]+=ax0*br.z; xr_[0][jb+3]+=ax0*br.w;
      xr_[1][jb+0]+=ax1*br.x; xr_[1][jb+1]+=ax1*br.y; xr_[1][jb+2]+=ax1*br.z; xr_[1][jb+3]+=ax1*br.w;
      xh[0][jb+0]+=ax0*bh.x; xh[0][jb+1]+=ax0*bh.y; xh[0][jb+2]+=ax0*bh.z; xh[0][jb+3]+=ax0*bh.w;
      xh[1][jb+0]+=ax1*bh.x; xh[1][jb+1]+=ax1*bh.y; xh[1][jb+2]+=ax1*bh.z; xh[1][jb+3]+=ax1*bh.w;
      hz[0][jb+0]+=ah0*cz.x; hz[0][jb+1]+=ah0*cz.y; hz[0][jb+2]+=ah0*cz.z; hz[0][jb+3]+=ah0*cz.w;
      hz[1][jb+0]+=ah1*cz.x; hz[1][jb+1]+=ah1*cz.y; hz[1][jb+2]+=ah1*cz.z; hz[1][jb+3]+=ah1*cz.w;
      hr[0][jb+0]+=ah0*cr.x; hr[0][jb+1]+=ah0*cr.y; hr[0][jb+2]+=ah0*cr.z; hr[0][jb+3]+=ah0*cr.w;
      hr[1][jb+0]+=ah1*cr.x; hr[1][jb+1]+=ah1*cr.y; hr[1][jb+2]+=ah1*cr.z; hr[1][jb+3]+=ah1*cr.w;
      hh[0][jb+0]+=ah0*ch.x; hh[0][jb+1]+=ah0*ch.y; hh[0][jb+2]+=ah0*ch.z; hh[0][jb+3]+=ah0*ch.w;
      hh[1][jb+0]+=ah1*ch.x; hh[1][jb+1]+=ah1*ch.y; hh[1][jb+2]+=ah1*ch.z; hh[1][jb+3]+=ah1*ch.w;
    }
  }

  const float4* gbv = (const float4*)gb;  // bias[0]: f4 0..95, bias[1]: f4 96..191
  #pragma unroll
  for (int i = 0; i < 2; ++i) {
    size_t e = (size_t)(e0 + r0 + i);
    #pragma unroll
    for (int j = 0; j < 2; ++j) {
      int c4 = tx + 16 * j;
      int jb = j * 4;
      float4 bz0 = gbv[c4],       br0 = gbv[32 + c4],  bh0 = gbv[64 + c4];
      float4 bz1 = gbv[96 + c4],  br1 = gbv[128 + c4], bh1 = gbv[160 + c4];
      float4 res;
      {
        float vz = sigmoidf_(xz[i][jb+0] + bz0.x + hz[i][jb+0] + bz1.x);
        float vr = sigmoidf_(xr_[i][jb+0] + br0.x + hr[i][jb+0] + br1.x);
        float th = tanhf_(xh[i][jb+0] + bh0.x + vr * (hh[i][jb+0] + bh1.x));
        float hv = Hs[(r0 + i) * ST + tx * 4 + 64 * j + 0];
        res.x = vz * hv + (1.f - vz) * th;
      }
      {
        float vz = sigmoidf_(xz[i][jb+1] + bz0.y + hz[i][jb+1] + bz1.y);
        float vr = sigmoidf_(xr_[i][jb+1] + br0.y + hr[i][jb+1] + br1.y);
        float th = tanhf_(xh[i][jb+1] + bh0.y + vr * (hh[i][jb+1] + bh1.y));
        float hv = Hs[(r0 + i) * ST + tx * 4 + 64 * j + 1];
        res.y = vz * hv + (1.f - vz) * th;
      }
      {
        float vz = sigmoidf_(xz[i][jb+2] + bz0.z + hz[i][jb+2] + bz1.z);
        float vr = sigmoidf_(xr_[i][jb+2] + br0.z + hr[i][jb+2] + br1.z);
        float th = tanhf_(xh[i][jb+2] + bh0.z + vr * (hh[i][jb+2] + bh1.z));
        float hv = Hs[(r0 + i) * ST + tx * 4 + 64 * j + 2];
        res.z = vz * hv + (1.f - vz) * th;
      }
      {
        float vz = sigmoidf_(xz[i][jb+3] + bz0.w + hz[i][jb+3] + bz1.w);
        float vr = sigmoidf_(xr_[i][jb+3] + br0.w + hr[i][jb+3] + br1.w);
        float th = tanhf_(xh[i][jb+3] + bh0.w + vr * (hh[i][jb+3] + bh1.w));
        float hv = Hs[(r0 + i) * ST + tx * 4 + 64 * j + 3];
        res.w = vz * hv + (1.f - vz) * th;
      }
      *(float4*)(h + e * DIM + tx * 4 + 64 * j) = res;
    }
  }
}

// ---------------- graph segment-sum (ids sorted) ----------------
// grid = NG, block = DIM
__global__ void graph_sum_kernel(const float* __restrict__ ls,
                                 const int* __restrict__ gids,
                                 float* __restrict__ gs) {
  int g = blockIdx.x, d = threadIdx.x;
  int lo = 0, hi = NUM_E;
  while (lo < hi) { int mid = (lo + hi) >> 1; if (gids[mid] < g) lo = mid + 1; else hi = mid; }
  int s0 = lo;
  hi = NUM_E;
  while (lo < hi) { int mid = (lo + hi) >> 1; if (gids[mid] < g + 1) lo = mid + 1; else hi = mid; }
  int s1 = lo;
  float s = 0.f;
  for (int e = s0; e < s1; ++e) s += ls[(size_t)e * DIM + d];
  gs[g * DIM + d] = s;
}

// ---------------- readout ----------------
__global__ __launch_bounds__(256) void readout1_kernel(
    const float* __restrict__ gs, const float* __restrict__ W,
    const float* __restrict__ b, float* __restrict__ r1) {
  __shared__ float sh[DIM];
  int g = blockIdx.x, c = threadIdx.x;
  if (c < DIM) sh[c] = gs[g * DIM + c];
  __syncthreads();
  float s = b[c];
  for (int k = 0; k < DIM; ++k) s += sh[k] * W[k * HID + c];
  r1[g * HID + c] = relu_(s);
}

__global__ __launch_bounds__(256) void readout2_kernel(
    const float* __restrict__ r1, const float* __restrict__ W,
    const float* __restrict__ b, float* __restrict__ r2) {
  __shared__ float sh[HID];
  int g = blockIdx.x, c = threadIdx.x;
  sh[c] = r1[g * HID + c];
  __syncthreads();
  float s = b[c];
  for (int k = 0; k < HID; ++k) s += sh[k] * W[k * HID + c];
  r2[g * HID + c] = relu_(s);
}

__global__ void readout3_kernel(const float* __restrict__ r2,
                                const float* __restrict__ W,
                                const float* __restrict__ b,
                                float* __restrict__ out) {
  int g = threadIdx.x;
  if (g < NG) {
    float s = b[0];
    for (int k = 0; k < HID; ++k) s += r2[g * HID + k] * W[k];
    out[g] = s;
  }
}

extern "C" void kernel_launch(void* const* d_in, const int* in_sizes, int n_in,
                              void* d_out, int out_size, void* d_ws, size_t ws_size,
                              hipStream_t stream) {
  float* ls          = (float*)d_in[0];        // mutated in place; harness restores
  const int* first   = (const int*)d_in[1];
  const int* second  = (const int*)d_in[2];
  const int* gids    = (const int*)d_in[3];
  const float* mW1   = (const float*)d_in[5];
  const float* mb1   = (const float*)d_in[6];
  const float* mW2   = (const float*)d_in[7];
  const float* mb2   = (const float*)d_in[8];
  const float* gk    = (const float*)d_in[9];
  const float* gr    = (const float*)d_in[10];
  const float* gb    = (const float*)d_in[11];
  const float* rW1   = (const float*)d_in[12];
  const float* rb1   = (const float*)d_in[13];
  const float* rW2   = (const float*)d_in[14];
  const float* rb2   = (const float*)d_in[15];
  const float* rW3   = (const float*)d_in[16];
  const float* rb3   = (const float*)d_in[17];
  float* out = (float*)d_out;

  float* edges = (float*)d_ws;                       // [E,128]
  float* gs    = edges + (size_t)NUM_E * DIM;        // [64,128]
  float* r1    = gs + NG * DIM;                      // [64,256]
  float* r2    = r1 + NG * HID;                      // [64,256]

  const int n4 = NUM_E * DIM / 4;
  for (int t = 0; t < TITER; ++t) {
    zero_kernel<<<(n4 + 255) / 256, 256, 0, stream>>>((float4*)edges, n4);
    msg_kernel<<<NUM_M / 64, 256, 0, stream>>>(ls, first, second, mW1, mb1, mW2, mb2, edges);
    gru_kernel<<<NUM_E / 32, 256, 0, stream>>>(edges, ls, gk, gr, gb);
  }
  graph_sum_kernel<<<NG, DIM, 0, stream>>>(ls, gids, gs);
  readout1_kernel<<<NG, HID, 0, stream>>>(gs, rW1, rb1, r1);
  readout2_kernel<<<NG, HID, 0, stream>>>(r1, rW2, rb2, r2);
  readout3_kernel<<<1, 64, 0, stream>>>(r2, rW3, rb3, out);
}

// Round 2
// 2159.193 us; speedup vs baseline: 2.3312x; 2.3312x over previous
//
#include <hip/hip_runtime.h>

#define NUM_E 100000
#define NUM_M 200000
#define DIM   128
#define HID   256
#define NG    64
#define TITER 3

typedef __attribute__((ext_vector_type(8))) short bf16x8;
typedef __attribute__((ext_vector_type(4))) float f32x4;

__device__ __forceinline__ unsigned short f2bf(float f) {
  unsigned u = __float_as_uint(f);
  u += 0x7FFF + ((u >> 16) & 1);          // RNE
  return (unsigned short)(u >> 16);
}
__device__ __forceinline__ float sigmoidf_(float v) {
  return 1.f / (1.f + __expf(-v));
}
__device__ __forceinline__ float tanhf_(float u) {
  u = fminf(fmaxf(u, -15.f), 15.f);
  float ex = __expf(-2.f * u);
  return (1.f - ex) / (1.f + ex);
}
__device__ __forceinline__ float relu_(float v) { return fmaxf(v, 0.f); }

#define MFMA(a, b, c) __builtin_amdgcn_mfma_f32_16x16x32_bf16((a), (b), (c), 0, 0, 0)

// ---------------- zero ----------------
__global__ void zero_kernel(float4* __restrict__ p, int n4) {
  int i = blockIdx.x * blockDim.x + threadIdx.x;
  if (i < n4) p[i] = make_float4(0.f, 0.f, 0.f, 0.f);
}

// ---------------- fp32 -> bf16 bulk convert ----------------
__global__ void cvt_bf_kernel(const float4* __restrict__ src,
                              ushort4* __restrict__ dst, int n4) {
  int i = blockIdx.x * blockDim.x + threadIdx.x;
  if (i < n4) {
    float4 v = src[i];
    ushort4 o;
    o.x = f2bf(v.x); o.y = f2bf(v.y); o.z = f2bf(v.z); o.w = f2bf(v.w);
    dst[i] = o;
  }
}

// ---------------- weight pack into MFMA A-fragment order ----------------
// A-frag layout (16x16x32): row n = lane&15, k = (lane>>4)*8 + j.
// dst chunk index = ((ks*NF + nf)*64 + lane), 8 bf16 per chunk.
// Source: logical W[k][n] = (k < KrowsA ? srcA[k][col_off+n] : srcB[k-KrowsA][col_off+n]),
// both row-major with leading dim src_ld.
__global__ void pack_w_kernel(const float* __restrict__ srcA,
                              const float* __restrict__ srcB, int KrowsA,
                              int K, int N, int src_ld, int col_off,
                              unsigned short* __restrict__ dst) {
  int idx = blockIdx.x * blockDim.x + threadIdx.x;   // one 8-elem chunk per thread
  int total = (K / 32) * (N / 16) * 64;
  if (idx >= total) return;
  int l = idx & 63;
  int t = idx >> 6;
  int NF = N / 16;
  int nf = t % NF;
  int ks = t / NF;
  int n = nf * 16 + (l & 15) + col_off;
  int k0 = ks * 32 + (l >> 4) * 8;
  unsigned short o[8];
  #pragma unroll
  for (int j = 0; j < 8; ++j) {
    int k = k0 + j;
    const float* src = (k < KrowsA) ? (srcA + (size_t)k * src_ld)
                                    : (srcB + (size_t)(k - KrowsA) * src_ld);
    o[j] = f2bf(src[n]);
  }
  ushort4* d = (ushort4*)(dst + (size_t)idx * 8);
  d[0] = make_ushort4(o[0], o[1], o[2], o[3]);
  d[1] = make_ushort4(o[4], o[5], o[6], o[7]);
}

// ---------------- message MLP (MFMA) + scatter ----------------
// block 256 = 4 waves; wave = 16 messages; grid = NUM_M/64.
// Role-swap: weights are the A operand, activations the B operand, so
// D^T comes out with n = quad*4+reg (contiguous per lane) and m = lane&15.
__global__ __launch_bounds__(256) void msg_kernel(
    const unsigned short* __restrict__ lsb,   // [E,128] bf16
    const int* __restrict__ first, const int* __restrict__ second,
    const unsigned short* __restrict__ W1p,   // packed [8][16][64][8]
    const float* __restrict__ b1,
    const unsigned short* __restrict__ W2p,   // packed [8][8][64][8]
    const float* __restrict__ b2,
    float* __restrict__ edges)
{
  constexpr int H1ST = 264;                  // bf16 stride (264*2 = 528 B, 16B-aligned)
  __shared__ unsigned short h1s[4][16 * H1ST];

  const int tid  = threadIdx.x;
  const int wave = tid >> 6;
  const int lane = tid & 63;
  const int c    = lane & 15;                // message index within wave tile
  const int quad = lane >> 4;
  const int m0   = blockIdx.x * 64 + wave * 16;

  const int f = first[m0 + c];
  const int s = second[m0 + c];

  // activation B-frags: k-steps 0..3 from ls[first], 4..7 from ls[second]
  bf16x8 act[8];
  const unsigned short* frow = lsb + (size_t)f * DIM + quad * 8;
  const unsigned short* srow = lsb + (size_t)s * DIM + quad * 8;
  #pragma unroll
  for (int ks = 0; ks < 4; ++ks) act[ks]     = *(const bf16x8*)(frow + ks * 32);
  #pragma unroll
  for (int ks = 0; ks < 4; ++ks) act[4 + ks] = *(const bf16x8*)(srow + ks * 32);

  // ---- layer 1: N=256 (16 frags), K=256 (8 k-steps) ----
  f32x4 acc[16];
  #pragma unroll
  for (int i = 0; i < 16; ++i) acc[i] = (f32x4)(0.f);

  const bf16x8* W1f = (const bf16x8*)W1p;
  #pragma unroll
  for (int ks = 0; ks < 8; ++ks) {
    #pragma unroll
    for (int nf = 0; nf < 16; ++nf) {
      bf16x8 wa = W1f[(ks * 16 + nf) * 64 + lane];
      acc[nf] = MFMA(wa, act[ks], acc[nf]);
    }
  }

  // epilogue 1: bias+relu, bf16, write to LDS as [m][n] (contiguous n per lane)
  #pragma unroll
  for (int nf = 0; nf < 16; ++nf) {
    int n0 = nf * 16 + quad * 4;
    float4 bv = *(const float4*)(b1 + n0);
    ushort4 pk;
    pk.x = f2bf(relu_(acc[nf][0] + bv.x));
    pk.y = f2bf(relu_(acc[nf][1] + bv.y));
    pk.z = f2bf(relu_(acc[nf][2] + bv.z));
    pk.w = f2bf(relu_(acc[nf][3] + bv.w));
    *(ushort4*)&h1s[wave][c * H1ST + n0] = pk;
  }
  __builtin_amdgcn_s_waitcnt(0);             // lgkm drain before wave-local reuse
  __builtin_amdgcn_wave_barrier();

  // ---- layer 2: N=128 (8 frags), K=256 (8 k-steps), B from LDS ----
  f32x4 acc2[8];
  #pragma unroll
  for (int i = 0; i < 8; ++i) acc2[i] = (f32x4)(0.f);

  const bf16x8* W2f = (const bf16x8*)W2p;
  #pragma unroll
  for (int ks = 0; ks < 8; ++ks) {
    bf16x8 bb = *(const bf16x8*)&h1s[wave][c * H1ST + ks * 32 + quad * 8];
    #pragma unroll
    for (int nf = 0; nf < 8; ++nf) {
      bf16x8 wa = W2f[(ks * 8 + nf) * 64 + lane];
      acc2[nf] = MFMA(wa, bb, acc2[nf]);
    }
  }

  // epilogue 2: bias+relu, atomic scatter-add into edges[second[m]]
  float* dst = edges + (size_t)s * DIM;
  #pragma unroll
  for (int nf = 0; nf < 8; ++nf) {
    int n0 = nf * 16 + quad * 4;
    float4 bv = *(const float4*)(b2 + n0);
    atomicAdd(&dst[n0 + 0], relu_(acc2[nf][0] + bv.x));
    atomicAdd(&dst[n0 + 1], relu_(acc2[nf][1] + bv.y));
    atomicAdd(&dst[n0 + 2], relu_(acc2[nf][2] + bv.z));
    atomicAdd(&dst[n0 + 3], relu_(acc2[nf][3] + bv.w));
  }
}

// ---------------- GRU (MFMA) ----------------
// block 256 = 4 waves; wave = 16 edges; grid = ceil(NUM_E/64). No LDS.
__global__ __launch_bounds__(256) void gru_kernel(
    const float* __restrict__ edges,          // x, fp32 [E,128]
    unsigned short* __restrict__ lsb,         // h bf16, in-place
    float* __restrict__ lsf,                  // h fp32 master, in-place
    const unsigned short* __restrict__ Wzrp,  // packed [8][16][64][8]
    const unsigned short* __restrict__ Wkhp,  // packed [4][8][64][8]
    const unsigned short* __restrict__ Wrhp,  // packed [4][8][64][8]
    const float* __restrict__ gb)             // [2][384]
{
  const int tid  = threadIdx.x;
  const int wave = tid >> 6;
  const int lane = tid & 63;
  const int c    = lane & 15;
  const int quad = lane >> 4;
  const int e0   = blockIdx.x * 64 + wave * 16;
  const int e    = e0 + c;
  const int ec   = min(e, NUM_E - 1);

  // B-frags: x (converted fp32->bf16) and h (bf16)
  bf16x8 xf[4], hf[4];
  const float* xrow = edges + (size_t)ec * DIM + quad * 8;
  #pragma unroll
  for (int ks = 0; ks < 4; ++ks) {
    float4 p0 = *(const float4*)(xrow + ks * 32);
    float4 p1 = *(const float4*)(xrow + ks * 32 + 4);
    bf16x8 v;
    v[0] = (short)f2bf(p0.x); v[1] = (short)f2bf(p0.y);
    v[2] = (short)f2bf(p0.z); v[3] = (short)f2bf(p0.w);
    v[4] = (short)f2bf(p1.x); v[5] = (short)f2bf(p1.y);
    v[6] = (short)f2bf(p1.z); v[7] = (short)f2bf(p1.w);
    xf[ks] = v;
  }
  const unsigned short* hrow = lsb + (size_t)ec * DIM + quad * 8;
  #pragma unroll
  for (int ks = 0; ks < 4; ++ks) hf[ks] = *(const bf16x8*)(hrow + ks * 32);

  // ---- zr gates: [x|h] @ [gk;gr][:, :256], N=256, K=256 ----
  f32x4 azr[16];
  #pragma unroll
  for (int i = 0; i < 16; ++i) azr[i] = (f32x4)(0.f);
  const bf16x8* Wzrf = (const bf16x8*)Wzrp;
  #pragma unroll
  for (int ks = 0; ks < 8; ++ks) {
    bf16x8 bb = (ks < 4) ? xf[ks] : hf[ks - 4];
    #pragma unroll
    for (int nf = 0; nf < 16; ++nf) {
      bf16x8 wa = Wzrf[(ks * 16 + nf) * 64 + lane];
      azr[nf] = MFMA(wa, bb, azr[nf]);
    }
  }

  // ---- h-gate: xh = x @ gk[:,256:], hh = h @ gr[:,256:], N=128, K=128 ----
  f32x4 axh[8], ahh[8];
  #pragma unroll
  for (int i = 0; i < 8; ++i) { axh[i] = (f32x4)(0.f); ahh[i] = (f32x4)(0.f); }
  const bf16x8* Wkhf = (const bf16x8*)Wkhp;
  const bf16x8* Wrhf = (const bf16x8*)Wrhp;
  #pragma unroll
  for (int ks = 0; ks < 4; ++ks) {
    #pragma unroll
    for (int nf = 0; nf < 8; ++nf) {
      axh[nf] = MFMA(Wkhf[(ks * 8 + nf) * 64 + lane], xf[ks], axh[nf]);
      ahh[nf] = MFMA(Wrhf[(ks * 8 + nf) * 64 + lane], hf[ks], ahh[nf]);
    }
  }

  if (e >= NUM_E) return;

  const float4* gbv = (const float4*)gb;
  #pragma unroll
  for (int nf = 0; nf < 8; ++nf) {
    int n0 = nf * 16 + quad * 4;
    int q4 = n0 >> 2;
    float4 b0z = gbv[q4],       b0r = gbv[32 + q4],  b0h = gbv[64 + q4];
    float4 b1z = gbv[96 + q4],  b1r = gbv[128 + q4], b1h = gbv[160 + q4];
    float4 hold = *(const float4*)(lsf + (size_t)e * DIM + n0);
    const float* pz  = (const float*)&azr[nf];
    const float* pr  = (const float*)&azr[nf + 8];
    const float* pxh = (const float*)&axh[nf];
    const float* phh = (const float*)&ahh[nf];
    const float* b0za = (const float*)&b0z; const float* b0ra = (const float*)&b0r;
    const float* b0ha = (const float*)&b0h; const float* b1za = (const float*)&b1z;
    const float* b1ra = (const float*)&b1r; const float* b1ha = (const float*)&b1h;
    const float* ho = (const float*)&hold;
    float outv[4];
    #pragma unroll
    for (int i = 0; i < 4; ++i) {
      float z  = sigmoidf_(pz[i] + b0za[i] + b1za[i]);
      float r  = sigmoidf_(pr[i] + b0ra[i] + b1ra[i]);
      float hc = tanhf_(pxh[i] + b0ha[i] + r * (phh[i] + b1ha[i]));
      outv[i] = z * ho[i] + (1.f - z) * hc;
    }
    *(float4*)(lsf + (size_t)e * DIM + n0) =
        make_float4(outv[0], outv[1], outv[2], outv[3]);
    ushort4 pk;
    pk.x = f2bf(outv[0]); pk.y = f2bf(outv[1]);
    pk.z = f2bf(outv[2]); pk.w = f2bf(outv[3]);
    *(ushort4*)(lsb + (size_t)e * DIM + n0) = pk;
  }
}

// ---------------- graph segment-sum (ids sorted) ----------------
__global__ void graph_sum_kernel(const float* __restrict__ ls,
                                 const int* __restrict__ gids,
                                 float* __restrict__ gs) {
  int g = blockIdx.x, d = threadIdx.x;
  int lo = 0, hi = NUM_E;
  while (lo < hi) { int mid = (lo + hi) >> 1; if (gids[mid] < g) lo = mid + 1; else hi = mid; }
  int s0 = lo;
  hi = NUM_E;
  while (lo < hi) { int mid = (lo + hi) >> 1; if (gids[mid] < g + 1) lo = mid + 1; else hi = mid; }
  int s1 = lo;
  float s = 0.f;
  for (int e = s0; e < s1; ++e) s += ls[(size_t)e * DIM + d];
  gs[g * DIM + d] = s;
}

// ---------------- readout ----------------
__global__ __launch_bounds__(256) void readout1_kernel(
    const float* __restrict__ gs, const float* __restrict__ W,
    const float* __restrict__ b, float* __restrict__ r1) {
  __shared__ float sh[DIM];
  int g = blockIdx.x, c = threadIdx.x;
  if (c < DIM) sh[c] = gs[g * DIM + c];
  __syncthreads();
  float s = b[c];
  for (int k = 0; k < DIM; ++k) s += sh[k] * W[k * HID + c];
  r1[g * HID + c] = relu_(s);
}

__global__ __launch_bounds__(256) void readout2_kernel(
    const float* __restrict__ r1, const float* __restrict__ W,
    const float* __restrict__ b, float* __restrict__ r2) {
  __shared__ float sh[HID];
  int g = blockIdx.x, c = threadIdx.x;
  sh[c] = r1[g * HID + c];
  __syncthreads();
  float s = b[c];
  for (int k = 0; k < HID; ++k) s += sh[k] * W[k * HID + c];
  r2[g * HID + c] = relu_(s);
}

__global__ void readout3_kernel(const float* __restrict__ r2,
                                const float* __restrict__ W,
                                const float* __restrict__ b,
                                float* __restrict__ out) {
  int g = threadIdx.x;
  if (g < NG) {
    float s = b[0];
    for (int k = 0; k < HID; ++k) s += r2[g * HID + k] * W[k];
    out[g] = s;
  }
}

extern "C" void kernel_launch(void* const* d_in, const int* in_sizes, int n_in,
                              void* d_out, int out_size, void* d_ws, size_t ws_size,
                              hipStream_t stream) {
  float* ls          = (float*)d_in[0];        // fp32 master h; harness restores
  const int* first   = (const int*)d_in[1];
  const int* second  = (const int*)d_in[2];
  const int* gids    = (const int*)d_in[3];
  const float* mW1   = (const float*)d_in[5];
  const float* mb1   = (const float*)d_in[6];
  const float* mW2   = (const float*)d_in[7];
  const float* mb2   = (const float*)d_in[8];
  const float* gk    = (const float*)d_in[9];
  const float* gr    = (const float*)d_in[10];
  const float* gb    = (const float*)d_in[11];
  const float* rW1   = (const float*)d_in[12];
  const float* rb1   = (const float*)d_in[13];
  const float* rW2   = (const float*)d_in[14];
  const float* rb2   = (const float*)d_in[15];
  const float* rW3   = (const float*)d_in[16];
  const float* rb3   = (const float*)d_in[17];
  float* out = (float*)d_out;

  // workspace layout
  char* w = (char*)d_ws;
  float* edges = (float*)w;                     w += (size_t)NUM_E * DIM * 4;   // 51.2 MB
  float* gs    = (float*)w;                     w += NG * DIM * 4;
  float* r1    = (float*)w;                     w += NG * HID * 4;
  float* r2    = (float*)w;                     w += NG * HID * 4;
  unsigned short* lsb  = (unsigned short*)w;    w += (size_t)NUM_E * DIM * 2;   // 25.6 MB
  unsigned short* W1p  = (unsigned short*)w;    w += 256 * 256 * 2;
  unsigned short* W2p  = (unsigned short*)w;    w += 256 * 128 * 2;
  unsigned short* Wzrp = (unsigned short*)w;    w += 256 * 256 * 2;
  unsigned short* Wkhp = (unsigned short*)w;    w += 128 * 128 * 2;
  unsigned short* Wrhp = (unsigned short*)w;    w += 128 * 128 * 2;

  // prep: bf16 link_state + packed weights (runs every call; graph-safe)
  const int n4 = NUM_E * DIM / 4;
  cvt_bf_kernel<<<(n4 + 255) / 256, 256, 0, stream>>>((const float4*)ls, (ushort4*)lsb, n4);
  pack_w_kernel<<<32, 256, 0, stream>>>(mW1, mW1, 256, 256, 256, 256, 0, W1p);
  pack_w_kernel<<<16, 256, 0, stream>>>(mW2, mW2, 256, 256, 128, 128, 0, W2p);
  pack_w_kernel<<<32, 256, 0, stream>>>(gk, gr, 128, 256, 256, 384, 0, Wzrp);
  pack_w_kernel<<<8, 256, 0, stream>>>(gk, gk, 128, 128, 128, 384, 256, Wkhp);
  pack_w_kernel<<<8, 256, 0, stream>>>(gr, gr, 128, 128, 128, 384, 256, Wrhp);

  const int gruBlocks = (NUM_E + 63) / 64;
  for (int t = 0; t < TITER; ++t) {
    zero_kernel<<<(n4 + 255) / 256, 256, 0, stream>>>((float4*)edges, n4);
    msg_kernel<<<NUM_M / 64, 256, 0, stream>>>(lsb, first, second, W1p, mb1, W2p, mb2, edges);
    gru_kernel<<<gruBlocks, 256, 0, stream>>>(edges, lsb, ls, Wzrp, Wkhp, Wrhp, gb);
  }
  graph_sum_kernel<<<NG, DIM, 0, stream>>>(ls, gids, gs);
  readout1_kernel<<<NG, HID, 0, stream>>>(gs, rW1, rb1, r1);
  readout2_kernel<<<NG, HID, 0, stream>>>(r1, rW2, rb2, r2);
  readout3_kernel<<<1, 64, 0, stream>>>(r2, rW3, rb3, out);
}

// Round 3
// 1324.920 us; speedup vs baseline: 3.7990x; 1.6297x over previous
//
#include <hip/hip_runtime.h>

#define NUM_E 100000
#define NUM_M 200000
#define DIM   128
#define HID   256
#define NG    64
#define TITER 3
#define NB_SCAN 98   // ceil(NUM_E/1024)

typedef __attribute__((ext_vector_type(8))) short bf16x8;
typedef __attribute__((ext_vector_type(4))) float f32x4;

__device__ __forceinline__ unsigned short f2bf(float f) {
  unsigned u = __float_as_uint(f);
  u += 0x7FFF + ((u >> 16) & 1);          // RNE
  return (unsigned short)(u >> 16);
}
__device__ __forceinline__ float bf2f(unsigned short h) {
  return __uint_as_float(((unsigned)h) << 16);
}
__device__ __forceinline__ float sigmoidf_(float v) {
  return 1.f / (1.f + __expf(-v));
}
__device__ __forceinline__ float tanhf_(float u) {
  u = fminf(fmaxf(u, -15.f), 15.f);
  float ex = __expf(-2.f * u);
  return (1.f - ex) / (1.f + ex);
}
__device__ __forceinline__ float relu_(float v) { return fmaxf(v, 0.f); }

#define MFMA(a, b, c) __builtin_amdgcn_mfma_f32_16x16x32_bf16((a), (b), (c), 0, 0, 0)

// ---------------- zero ----------------
__global__ void zero_kernel(float4* __restrict__ p, int n4) {
  int i = blockIdx.x * blockDim.x + threadIdx.x;
  if (i < n4) p[i] = make_float4(0.f, 0.f, 0.f, 0.f);
}

// ---------------- fp32 -> bf16 bulk convert ----------------
__global__ void cvt_bf_kernel(const float4* __restrict__ src,
                              ushort4* __restrict__ dst, int n4) {
  int i = blockIdx.x * blockDim.x + threadIdx.x;
  if (i < n4) {
    float4 v = src[i];
    ushort4 o;
    o.x = f2bf(v.x); o.y = f2bf(v.y); o.z = f2bf(v.z); o.w = f2bf(v.w);
    dst[i] = o;
  }
}

// ---------------- CSR build: histogram / scan / scatter ----------------
__global__ void hist_kernel(const int* __restrict__ second, int* __restrict__ counts) {
  int m = blockIdx.x * blockDim.x + threadIdx.x;
  if (m < NUM_M) atomicAdd(&counts[second[m]], 1);
}

// block scan over 1024-elem chunks (256 thr x 4)
__global__ __launch_bounds__(256) void scan1_kernel(const int* __restrict__ counts,
                                                    int* __restrict__ partials) {
  __shared__ int sh[256];
  int b = blockIdx.x, t = threadIdx.x;
  int i0 = b * 1024 + t * 4;
  int c0 = (i0 + 0 < NUM_E) ? counts[i0 + 0] : 0;
  int c1 = (i0 + 1 < NUM_E) ? counts[i0 + 1] : 0;
  int c2 = (i0 + 2 < NUM_E) ? counts[i0 + 2] : 0;
  int c3 = (i0 + 3 < NUM_E) ? counts[i0 + 3] : 0;
  int tsum = c0 + c1 + c2 + c3;
  sh[t] = tsum;
  __syncthreads();
  for (int off = 1; off < 256; off <<= 1) {
    int v = (t >= off) ? sh[t - off] : 0;
    __syncthreads();
    sh[t] += v;
    __syncthreads();
  }
  if (t == 255) partials[b] = sh[255];
}

__global__ void scan2_kernel(const int* __restrict__ partials, int* __restrict__ base,
                             int* __restrict__ rowptr) {
  if (threadIdx.x == 0) {
    int run = 0;
    for (int b = 0; b < NB_SCAN; ++b) { base[b] = run; run += partials[b]; }
    rowptr[NUM_E] = NUM_M;
  }
}

__global__ __launch_bounds__(256) void scan3_kernel(const int* __restrict__ counts,
                                                    const int* __restrict__ base,
                                                    int* __restrict__ rowptr) {
  __shared__ int sh[256];
  int b = blockIdx.x, t = threadIdx.x;
  int i0 = b * 1024 + t * 4;
  int c0 = (i0 + 0 < NUM_E) ? counts[i0 + 0] : 0;
  int c1 = (i0 + 1 < NUM_E) ? counts[i0 + 1] : 0;
  int c2 = (i0 + 2 < NUM_E) ? counts[i0 + 2] : 0;
  int c3 = (i0 + 3 < NUM_E) ? counts[i0 + 3] : 0;
  int tsum = c0 + c1 + c2 + c3;
  sh[t] = tsum;
  __syncthreads();
  for (int off = 1; off < 256; off <<= 1) {
    int v = (t >= off) ? sh[t - off] : 0;
    __syncthreads();
    sh[t] += v;
    __syncthreads();
  }
  int p = base[b] + (sh[t] - tsum);
  if (i0 + 0 < NUM_E) rowptr[i0 + 0] = p;
  if (i0 + 1 < NUM_E) rowptr[i0 + 1] = p + c0;
  if (i0 + 2 < NUM_E) rowptr[i0 + 2] = p + c0 + c1;
  if (i0 + 3 < NUM_E) rowptr[i0 + 3] = p + c0 + c1 + c2;
}

__global__ void scatter_kernel(const int* __restrict__ second,
                               const int* __restrict__ rowptr,
                               int* __restrict__ cursor, int* __restrict__ order) {
  int m = blockIdx.x * blockDim.x + threadIdx.x;
  if (m < NUM_M) {
    int e = second[m];
    int pos = atomicAdd(&cursor[e], 1);
    order[rowptr[e] + pos] = m;
  }
}

// ---------------- weight pack into MFMA A-fragment order ----------------
__global__ void pack_w_kernel(const float* __restrict__ srcA,
                              const float* __restrict__ srcB, int KrowsA,
                              int K, int N, int src_ld, int col_off,
                              unsigned short* __restrict__ dst) {
  int idx = blockIdx.x * blockDim.x + threadIdx.x;   // one 8-elem chunk per thread
  int total = (K / 32) * (N / 16) * 64;
  if (idx >= total) return;
  int l = idx & 63;
  int t = idx >> 6;
  int NF = N / 16;
  int nf = t % NF;
  int ks = t / NF;
  int n = nf * 16 + (l & 15) + col_off;
  int k0 = ks * 32 + (l >> 4) * 8;
  unsigned short o[8];
  #pragma unroll
  for (int j = 0; j < 8; ++j) {
    int k = k0 + j;
    const float* src = (k < KrowsA) ? (srcA + (size_t)k * src_ld)
                                    : (srcB + (size_t)(k - KrowsA) * src_ld);
    o[j] = f2bf(src[n]);
  }
  ushort4* d = (ushort4*)(dst + (size_t)idx * 8);
  d[0] = make_ushort4(o[0], o[1], o[2], o[3]);
  d[1] = make_ushort4(o[4], o[5], o[6], o[7]);
}

// ---------------- message MLP (MFMA), 32 msgs/wave, no atomics ----------------
// block 256 = 4 waves; wave = 32 messages (2 B-sets sharing weight loads);
// grid = ceil(NUM_M/128). Output: bf16 rows msgout[m][128].
__global__ __launch_bounds__(256, 2) void msg_kernel(
    const unsigned short* __restrict__ lsb,   // [E,128] bf16
    const int* __restrict__ first, const int* __restrict__ second,
    const unsigned short* __restrict__ W1p,   // packed [8][16][64][8]
    const float* __restrict__ b1,
    const unsigned short* __restrict__ W2p,   // packed [8][8][64][8]
    const float* __restrict__ b2,
    unsigned short* __restrict__ msgout)
{
  constexpr int H1ST = 264;                  // ushort stride; 2-way bank alias only
  __shared__ unsigned short h1s[4][32 * H1ST];   // 67.6 KB

  const int tid  = threadIdx.x;
  const int wave = tid >> 6;
  const int lane = tid & 63;
  const int c    = lane & 15;
  const int quad = lane >> 4;
  const int m0   = blockIdx.x * 128 + wave * 32;

  const int mA = min(m0 + c,      NUM_M - 1);
  const int mB = min(m0 + 16 + c, NUM_M - 1);
  const int fA = first[mA],  sA = second[mA];
  const int fB = first[mB],  sB = second[mB];

  // activation B-frags for both sets
  bf16x8 actA[8], actB[8];
  {
    const unsigned short* fra = lsb + (size_t)fA * DIM + quad * 8;
    const unsigned short* sra = lsb + (size_t)sA * DIM + quad * 8;
    const unsigned short* frb = lsb + (size_t)fB * DIM + quad * 8;
    const unsigned short* srb = lsb + (size_t)sB * DIM + quad * 8;
    #pragma unroll
    for (int ks = 0; ks < 4; ++ks) {
      actA[ks]     = *(const bf16x8*)(fra + ks * 32);
      actA[4 + ks] = *(const bf16x8*)(sra + ks * 32);
      actB[ks]     = *(const bf16x8*)(frb + ks * 32);
      actB[4 + ks] = *(const bf16x8*)(srb + ks * 32);
    }
  }

  // ---- layer 1: N=256 (16 frags), K=256 (8 k-steps), 2 msg-sets ----
  f32x4 accA[16], accB[16];
  #pragma unroll
  for (int i = 0; i < 16; ++i) { accA[i] = (f32x4)(0.f); accB[i] = (f32x4)(0.f); }

  const bf16x8* W1f = (const bf16x8*)W1p;
  #pragma unroll
  for (int ks = 0; ks < 8; ++ks) {
    #pragma unroll
    for (int nf = 0; nf < 16; ++nf) {
      bf16x8 wa = W1f[(ks * 16 + nf) * 64 + lane];
      accA[nf] = MFMA(wa, actA[ks], accA[nf]);
      accB[nf] = MFMA(wa, actB[ks], accB[nf]);
    }
  }

  // epilogue 1: bias+relu -> bf16 -> LDS [row=set*16+c][n]
  #pragma unroll
  for (int nf = 0; nf < 16; ++nf) {
    int n0 = nf * 16 + quad * 4;
    float4 bv = *(const float4*)(b1 + n0);
    ushort4 pa, pb;
    pa.x = f2bf(relu_(accA[nf][0] + bv.x));
    pa.y = f2bf(relu_(accA[nf][1] + bv.y));
    pa.z = f2bf(relu_(accA[nf][2] + bv.z));
    pa.w = f2bf(relu_(accA[nf][3] + bv.w));
    pb.x = f2bf(relu_(accB[nf][0] + bv.x));
    pb.y = f2bf(relu_(accB[nf][1] + bv.y));
    pb.z = f2bf(relu_(accB[nf][2] + bv.z));
    pb.w = f2bf(relu_(accB[nf][3] + bv.w));
    *(ushort4*)&h1s[wave][(c)      * H1ST + n0] = pa;
    *(ushort4*)&h1s[wave][(16 + c) * H1ST + n0] = pb;
  }
  __builtin_amdgcn_s_waitcnt(0);             // wave-local LDS drain
  __builtin_amdgcn_wave_barrier();

  // ---- layer 2: N=128 (8 frags), K=256 (8 k-steps) ----
  f32x4 acc2A[8], acc2B[8];
  #pragma unroll
  for (int i = 0; i < 8; ++i) { acc2A[i] = (f32x4)(0.f); acc2B[i] = (f32x4)(0.f); }

  const bf16x8* W2f = (const bf16x8*)W2p;
  #pragma unroll
  for (int ks = 0; ks < 8; ++ks) {
    bf16x8 bbA = *(const bf16x8*)&h1s[wave][(c)      * H1ST + ks * 32 + quad * 8];
    bf16x8 bbB = *(const bf16x8*)&h1s[wave][(16 + c) * H1ST + ks * 32 + quad * 8];
    #pragma unroll
    for (int nf = 0; nf < 8; ++nf) {
      bf16x8 wa = W2f[(ks * 8 + nf) * 64 + lane];
      acc2A[nf] = MFMA(wa, bbA, acc2A[nf]);
      acc2B[nf] = MFMA(wa, bbB, acc2B[nf]);
    }
  }

  // epilogue 2: bias+relu -> bf16 rows (guarded plain stores)
  #pragma unroll
  for (int set = 0; set < 2; ++set) {
    int m = m0 + set * 16 + c;
    if (m >= NUM_M) continue;
    unsigned short* dst = msgout + (size_t)m * DIM;
    f32x4* a2 = set ? acc2B : acc2A;
    #pragma unroll
    for (int nf = 0; nf < 8; ++nf) {
      int n0 = nf * 16 + quad * 4;
      float4 bv = *(const float4*)(b2 + n0);
      ushort4 pk;
      pk.x = f2bf(relu_(a2[nf][0] + bv.x));
      pk.y = f2bf(relu_(a2[nf][1] + bv.y));
      pk.z = f2bf(relu_(a2[nf][2] + bv.z));
      pk.w = f2bf(relu_(a2[nf][3] + bv.w));
      *(ushort4*)(dst + n0) = pk;
    }
  }
}

// ---------------- GRU (MFMA) with fused CSR segment-sum ----------------
__global__ __launch_bounds__(256) void gru_kernel(
    const unsigned short* __restrict__ msgb,  // [M,128] bf16
    const int* __restrict__ rowptr,           // [E+1]
    const int* __restrict__ order,            // [M]
    unsigned short* __restrict__ lsb,         // h bf16, in-place
    float* __restrict__ lsf,                  // h fp32 master, in-place
    const unsigned short* __restrict__ Wzrp,  // packed [8][16][64][8]
    const unsigned short* __restrict__ Wkhp,  // packed [4][8][64][8]
    const unsigned short* __restrict__ Wrhp,  // packed [4][8][64][8]
    const float* __restrict__ gb)             // [2][384]
{
  const int tid  = threadIdx.x;
  const int wave = tid >> 6;
  const int lane = tid & 63;
  const int c    = lane & 15;
  const int quad = lane >> 4;
  const int e0   = blockIdx.x * 64 + wave * 16;
  const int e    = e0 + c;
  const int ec   = min(e, NUM_E - 1);

  // fused segment-sum: x[ec] = sum over CSR list of bf16 msg rows (fp32 acc)
  float xacc[4][8];
  #pragma unroll
  for (int ks = 0; ks < 4; ++ks)
    #pragma unroll
    for (int j = 0; j < 8; ++j) xacc[ks][j] = 0.f;

  const int rs = rowptr[ec], re = rowptr[ec + 1];
  for (int p = rs; p < re; ++p) {
    int m = order[p];
    const unsigned short* mr = msgb + (size_t)m * DIM + quad * 8;
    #pragma unroll
    for (int ks = 0; ks < 4; ++ks) {
      bf16x8 v = *(const bf16x8*)(mr + ks * 32);
      #pragma unroll
      for (int j = 0; j < 8; ++j)
        xacc[ks][j] += bf2f((unsigned short)v[j]);
    }
  }

  bf16x8 xf[4], hf[4];
  #pragma unroll
  for (int ks = 0; ks < 4; ++ks) {
    bf16x8 v;
    #pragma unroll
    for (int j = 0; j < 8; ++j) v[j] = (short)f2bf(xacc[ks][j]);
    xf[ks] = v;
  }
  const unsigned short* hrow = lsb + (size_t)ec * DIM + quad * 8;
  #pragma unroll
  for (int ks = 0; ks < 4; ++ks) hf[ks] = *(const bf16x8*)(hrow + ks * 32);

  // ---- zr gates: [x|h] @ [gk;gr][:, :256], N=256, K=256 ----
  f32x4 azr[16];
  #pragma unroll
  for (int i = 0; i < 16; ++i) azr[i] = (f32x4)(0.f);
  const bf16x8* Wzrf = (const bf16x8*)Wzrp;
  #pragma unroll
  for (int ks = 0; ks < 8; ++ks) {
    bf16x8 bb = (ks < 4) ? xf[ks] : hf[ks - 4];
    #pragma unroll
    for (int nf = 0; nf < 16; ++nf) {
      bf16x8 wa = Wzrf[(ks * 16 + nf) * 64 + lane];
      azr[nf] = MFMA(wa, bb, azr[nf]);
    }
  }

  // ---- h-gate: xh = x @ gk[:,256:], hh = h @ gr[:,256:], N=128, K=128 ----
  f32x4 axh[8], ahh[8];
  #pragma unroll
  for (int i = 0; i < 8; ++i) { axh[i] = (f32x4)(0.f); ahh[i] = (f32x4)(0.f); }
  const bf16x8* Wkhf = (const bf16x8*)Wkhp;
  const bf16x8* Wrhf = (const bf16x8*)Wrhp;
  #pragma unroll
  for (int ks = 0; ks < 4; ++ks) {
    #pragma unroll
    for (int nf = 0; nf < 8; ++nf) {
      axh[nf] = MFMA(Wkhf[(ks * 8 + nf) * 64 + lane], xf[ks], axh[nf]);
      ahh[nf] = MFMA(Wrhf[(ks * 8 + nf) * 64 + lane], hf[ks], ahh[nf]);
    }
  }

  if (e >= NUM_E) return;

  const float4* gbv = (const float4*)gb;
  #pragma unroll
  for (int nf = 0; nf < 8; ++nf) {
    int n0 = nf * 16 + quad * 4;
    int q4 = n0 >> 2;
    float4 b0z = gbv[q4],       b0r = gbv[32 + q4],  b0h = gbv[64 + q4];
    float4 b1z = gbv[96 + q4],  b1r = gbv[128 + q4], b1h = gbv[160 + q4];
    float4 hold = *(const float4*)(lsf + (size_t)e * DIM + n0);
    const float* pz  = (const float*)&azr[nf];
    const float* pr  = (const float*)&azr[nf + 8];
    const float* pxh = (const float*)&axh[nf];
    const float* phh = (const float*)&ahh[nf];
    const float* b0za = (const float*)&b0z; const float* b0ra = (const float*)&b0r;
    const float* b0ha = (const float*)&b0h; const float* b1za = (const float*)&b1z;
    const float* b1ra = (const float*)&b1r; const float* b1ha = (const float*)&b1h;
    const float* ho = (const float*)&hold;
    float outv[4];
    #pragma unroll
    for (int i = 0; i < 4; ++i) {
      float z  = sigmoidf_(pz[i] + b0za[i] + b1za[i]);
      float r  = sigmoidf_(pr[i] + b0ra[i] + b1ra[i]);
      float hc = tanhf_(pxh[i] + b0ha[i] + r * (phh[i] + b1ha[i]));
      outv[i] = z * ho[i] + (1.f - z) * hc;
    }
    *(float4*)(lsf + (size_t)e * DIM + n0) =
        make_float4(outv[0], outv[1], outv[2], outv[3]);
    ushort4 pk;
    pk.x = f2bf(outv[0]); pk.y = f2bf(outv[1]);
    pk.z = f2bf(outv[2]); pk.w = f2bf(outv[3]);
    *(ushort4*)(lsb + (size_t)e * DIM + n0) = pk;
  }
}

// ---------------- graph segment-sum (ids sorted) ----------------
__global__ void graph_sum_kernel(const float* __restrict__ ls,
                                 const int* __restrict__ gids,
                                 float* __restrict__ gs) {
  int g = blockIdx.x, d = threadIdx.x;
  int lo = 0, hi = NUM_E;
  while (lo < hi) { int mid = (lo + hi) >> 1; if (gids[mid] < g) lo = mid + 1; else hi = mid; }
  int s0 = lo;
  hi = NUM_E;
  while (lo < hi) { int mid = (lo + hi) >> 1; if (gids[mid] < g + 1) lo = mid + 1; else hi = mid; }
  int s1 = lo;
  float s = 0.f;
  for (int e = s0; e < s1; ++e) s += ls[(size_t)e * DIM + d];
  gs[g * DIM + d] = s;
}

// ---------------- readout ----------------
__global__ __launch_bounds__(256) void readout1_kernel(
    const float* __restrict__ gs, const float* __restrict__ W,
    const float* __restrict__ b, float* __restrict__ r1) {
  __shared__ float sh[DIM];
  int g = blockIdx.x, c = threadIdx.x;
  if (c < DIM) sh[c] = gs[g * DIM + c];
  __syncthreads();
  float s = b[c];
  for (int k = 0; k < DIM; ++k) s += sh[k] * W[k * HID + c];
  r1[g * HID + c] = relu_(s);
}

__global__ __launch_bounds__(256) void readout2_kernel(
    const float* __restrict__ r1, const float* __restrict__ W,
    const float* __restrict__ b, float* __restrict__ r2) {
  __shared__ float sh[HID];
  int g = blockIdx.x, c = threadIdx.x;
  sh[c] = r1[g * HID + c];
  __syncthreads();
  float s = b[c];
  for (int k = 0; k < HID; ++k) s += sh[k] * W[k * HID + c];
  r2[g * HID + c] = relu_(s);
}

__global__ void readout3_kernel(const float* __restrict__ r2,
                                const float* __restrict__ W,
                                const float* __restrict__ b,
                                float* __restrict__ out) {
  int g = threadIdx.x;
  if (g < NG) {
    float s = b[0];
    for (int k = 0; k < HID; ++k) s += r2[g * HID + k] * W[k];
    out[g] = s;
  }
}

extern "C" void kernel_launch(void* const* d_in, const int* in_sizes, int n_in,
                              void* d_out, int out_size, void* d_ws, size_t ws_size,
                              hipStream_t stream) {
  float* ls          = (float*)d_in[0];        // fp32 master h; harness restores
  const int* first   = (const int*)d_in[1];
  const int* second  = (const int*)d_in[2];
  const int* gids    = (const int*)d_in[3];
  const float* mW1   = (const float*)d_in[5];
  const float* mb1   = (const float*)d_in[6];
  const float* mW2   = (const float*)d_in[7];
  const float* mb2   = (const float*)d_in[8];
  const float* gk    = (const float*)d_in[9];
  const float* gr    = (const float*)d_in[10];
  const float* gb    = (const float*)d_in[11];
  const float* rW1   = (const float*)d_in[12];
  const float* rb1   = (const float*)d_in[13];
  const float* rW2   = (const float*)d_in[14];
  const float* rb2   = (const float*)d_in[15];
  const float* rW3   = (const float*)d_in[16];
  const float* rb3   = (const float*)d_in[17];
  float* out = (float*)d_out;

  // workspace layout
  char* w = (char*)d_ws;
  unsigned short* msgb = (unsigned short*)w;    w += (size_t)NUM_M * DIM * 2;   // 51.2 MB
  unsigned short* lsb  = (unsigned short*)w;    w += (size_t)NUM_E * DIM * 2;   // 25.6 MB
  float* gs    = (float*)w;                     w += NG * DIM * 4;
  float* r1    = (float*)w;                     w += NG * HID * 4;
  float* r2    = (float*)w;                     w += NG * HID * 4;
  int* counts  = (int*)w;                       w += NUM_E * 4;
  int* cursor  = (int*)w;                       w += NUM_E * 4;
  int* rowptr  = (int*)w;                       w += (NUM_E + 4) * 4;
  int* order   = (int*)w;                       w += NUM_M * 4;
  int* partials= (int*)w;                       w += NB_SCAN * 4;
  int* basep   = (int*)w;                       w += NB_SCAN * 4;
  unsigned short* W1p  = (unsigned short*)w;    w += 256 * 256 * 2;
  unsigned short* W2p  = (unsigned short*)w;    w += 256 * 128 * 2;
  unsigned short* Wzrp = (unsigned short*)w;    w += 256 * 256 * 2;
  unsigned short* Wkhp = (unsigned short*)w;    w += 128 * 128 * 2;
  unsigned short* Wrhp = (unsigned short*)w;    w += 128 * 128 * 2;

  // prep: bf16 link_state + packed weights
  const int n4 = NUM_E * DIM / 4;
  cvt_bf_kernel<<<(n4 + 255) / 256, 256, 0, stream>>>((const float4*)ls, (ushort4*)lsb, n4);
  pack_w_kernel<<<32, 256, 0, stream>>>(mW1, mW1, 256, 256, 256, 256, 0, W1p);
  pack_w_kernel<<<16, 256, 0, stream>>>(mW2, mW2, 256, 256, 128, 128, 0, W2p);
  pack_w_kernel<<<32, 256, 0, stream>>>(gk, gr, 128, 256, 256, 384, 0, Wzrp);
  pack_w_kernel<<<8, 256, 0, stream>>>(gk, gk, 128, 128, 128, 384, 256, Wkhp);
  pack_w_kernel<<<8, 256, 0, stream>>>(gr, gr, 128, 128, 128, 384, 256, Wrhp);

  // CSR build (counts+cursor zeroed together: 2*NUM_E ints = 200000 = 50000 f4)
  zero_kernel<<<(2 * NUM_E / 4 + 255) / 256, 256, 0, stream>>>((float4*)counts, 2 * NUM_E / 4);
  hist_kernel<<<(NUM_M + 255) / 256, 256, 0, stream>>>(second, counts);
  scan1_kernel<<<NB_SCAN, 256, 0, stream>>>(counts, partials);
  scan2_kernel<<<1, 64, 0, stream>>>(partials, basep, rowptr);
  scan3_kernel<<<NB_SCAN, 256, 0, stream>>>(counts, basep, rowptr);
  scatter_kernel<<<(NUM_M + 255) / 256, 256, 0, stream>>>(second, rowptr, cursor, order);

  const int msgBlocks = (NUM_M + 127) / 128;
  const int gruBlocks = (NUM_E + 63) / 64;
  for (int t = 0; t < TITER; ++t) {
    msg_kernel<<<msgBlocks, 256, 0, stream>>>(lsb, first, second, W1p, mb1, W2p, mb2, msgb);
    gru_kernel<<<gruBlocks, 256, 0, stream>>>(msgb, rowptr, order, lsb, ls, Wzrp, Wkhp, Wrhp, gb);
  }
  graph_sum_kernel<<<NG, DIM, 0, stream>>>(ls, gids, gs);
  readout1_kernel<<<NG, HID, 0, stream>>>(gs, rW1, rb1, r1);
  readout2_kernel<<<NG, HID, 0, stream>>>(r1, rW2, rb2, r2);
  readout3_kernel<<<1, 64, 0, stream>>>(r2, rW3, rb3, out);
}

// Round 4
// 976.758 us; speedup vs baseline: 5.1532x; 1.3564x over previous
//
#include <hip/hip_runtime.h>

#define NUM_E 100000
#define NUM_M 200000
#define DIM   128
#define HID   256
#define NG    64
#define TITER 3
#define NB_SCAN 98   // ceil(NUM_E/1024)
#define GS_ER 128    // edges per block in graph_sum

typedef __attribute__((ext_vector_type(8))) short bf16x8;
typedef __attribute__((ext_vector_type(4))) float f32x4;

__device__ __forceinline__ unsigned short f2bf(float f) {
  unsigned u = __float_as_uint(f);
  u += 0x7FFF + ((u >> 16) & 1);          // RNE
  return (unsigned short)(u >> 16);
}
__device__ __forceinline__ float bf2f(unsigned short h) {
  return __uint_as_float(((unsigned)h) << 16);
}
__device__ __forceinline__ float sigmoidf_(float v) {
  return 1.f / (1.f + __expf(-v));
}
__device__ __forceinline__ float tanhf_(float u) {
  u = fminf(fmaxf(u, -15.f), 15.f);
  float ex = __expf(-2.f * u);
  return (1.f - ex) / (1.f + ex);
}
__device__ __forceinline__ float relu_(float v) { return fmaxf(v, 0.f); }

#define MFMA(a, b, c) __builtin_amdgcn_mfma_f32_16x16x32_bf16((a), (b), (c), 0, 0, 0)

// ---------------- zero ----------------
__global__ void zero_kernel(float4* __restrict__ p, int n4) {
  int i = blockIdx.x * blockDim.x + threadIdx.x;
  if (i < n4) p[i] = make_float4(0.f, 0.f, 0.f, 0.f);
}

// ---------------- fp32 -> bf16 bulk convert ----------------
__global__ void cvt_bf_kernel(const float4* __restrict__ src,
                              ushort4* __restrict__ dst, int n4) {
  int i = blockIdx.x * blockDim.x + threadIdx.x;
  if (i < n4) {
    float4 v = src[i];
    ushort4 o;
    o.x = f2bf(v.x); o.y = f2bf(v.y); o.z = f2bf(v.z); o.w = f2bf(v.w);
    dst[i] = o;
  }
}

// ---------------- CSR build: histogram / scan / scatter ----------------
__global__ void hist_kernel(const int* __restrict__ second, int* __restrict__ counts) {
  int m = blockIdx.x * blockDim.x + threadIdx.x;
  if (m < NUM_M) atomicAdd(&counts[second[m]], 1);
}

// block scan over 1024-elem chunks (256 thr x 4)
__global__ __launch_bounds__(256) void scan1_kernel(const int* __restrict__ counts,
                                                    int* __restrict__ partials) {
  __shared__ int sh[256];
  int b = blockIdx.x, t = threadIdx.x;
  int i0 = b * 1024 + t * 4;
  int c0 = (i0 + 0 < NUM_E) ? counts[i0 + 0] : 0;
  int c1 = (i0 + 1 < NUM_E) ? counts[i0 + 1] : 0;
  int c2 = (i0 + 2 < NUM_E) ? counts[i0 + 2] : 0;
  int c3 = (i0 + 3 < NUM_E) ? counts[i0 + 3] : 0;
  int tsum = c0 + c1 + c2 + c3;
  sh[t] = tsum;
  __syncthreads();
  for (int off = 1; off < 256; off <<= 1) {
    int v = (t >= off) ? sh[t - off] : 0;
    __syncthreads();
    sh[t] += v;
    __syncthreads();
  }
  if (t == 255) partials[b] = sh[255];
}

__global__ void scan2_kernel(const int* __restrict__ partials, int* __restrict__ base,
                             int* __restrict__ rowptr) {
  if (threadIdx.x == 0) {
    int run = 0;
    for (int b = 0; b < NB_SCAN; ++b) { base[b] = run; run += partials[b]; }
    rowptr[NUM_E] = NUM_M;
  }
}

__global__ __launch_bounds__(256) void scan3_kernel(const int* __restrict__ counts,
                                                    const int* __restrict__ base,
                                                    int* __restrict__ rowptr) {
  __shared__ int sh[256];
  int b = blockIdx.x, t = threadIdx.x;
  int i0 = b * 1024 + t * 4;
  int c0 = (i0 + 0 < NUM_E) ? counts[i0 + 0] : 0;
  int c1 = (i0 + 1 < NUM_E) ? counts[i0 + 1] : 0;
  int c2 = (i0 + 2 < NUM_E) ? counts[i0 + 2] : 0;
  int c3 = (i0 + 3 < NUM_E) ? counts[i0 + 3] : 0;
  int tsum = c0 + c1 + c2 + c3;
  sh[t] = tsum;
  __syncthreads();
  for (int off = 1; off < 256; off <<= 1) {
    int v = (t >= off) ? sh[t - off] : 0;
    __syncthreads();
    sh[t] += v;
    __syncthreads();
  }
  int p = base[b] + (sh[t] - tsum);
  if (i0 + 0 < NUM_E) rowptr[i0 + 0] = p;
  if (i0 + 1 < NUM_E) rowptr[i0 + 1] = p + c0;
  if (i0 + 2 < NUM_E) rowptr[i0 + 2] = p + c0 + c1;
  if (i0 + 3 < NUM_E) rowptr[i0 + 3] = p + c0 + c1 + c2;
}

__global__ void scatter_kernel(const int* __restrict__ second,
                               const int* __restrict__ rowptr,
                               int* __restrict__ cursor, int* __restrict__ order) {
  int m = blockIdx.x * blockDim.x + threadIdx.x;
  if (m < NUM_M) {
    int e = second[m];
    int pos = atomicAdd(&cursor[e], 1);
    order[rowptr[e] + pos] = m;
  }
}

// ---------------- weight pack into MFMA A-fragment order ----------------
__global__ void pack_w_kernel(const float* __restrict__ srcA,
                              const float* __restrict__ srcB, int KrowsA,
                              int K, int N, int src_ld, int col_off,
                              unsigned short* __restrict__ dst) {
  int idx = blockIdx.x * blockDim.x + threadIdx.x;   // one 8-elem chunk per thread
  int total = (K / 32) * (N / 16) * 64;
  if (idx >= total) return;
  int l = idx & 63;
  int t = idx >> 6;
  int NF = N / 16;
  int nf = t % NF;
  int ks = t / NF;
  int n = nf * 16 + (l & 15) + col_off;
  int k0 = ks * 32 + (l >> 4) * 8;
  unsigned short o[8];
  #pragma unroll
  for (int j = 0; j < 8; ++j) {
    int k = k0 + j;
    const float* src = (k < KrowsA) ? (srcA + (size_t)k * src_ld)
                                    : (srcB + (size_t)(k - KrowsA) * src_ld);
    o[j] = f2bf(src[n]);
  }
  ushort4* d = (ushort4*)(dst + (size_t)idx * 8);
  d[0] = make_ushort4(o[0], o[1], o[2], o[3]);
  d[1] = make_ushort4(o[4], o[5], o[6], o[7]);
}

// ---------------- message MLP (MFMA), 32 msgs/wave, no atomics ----------------
__global__ __launch_bounds__(256, 2) void msg_kernel(
    const unsigned short* __restrict__ lsb,   // [E,128] bf16
    const int* __restrict__ first, const int* __restrict__ second,
    const unsigned short* __restrict__ W1p,   // packed [8][16][64][8]
    const float* __restrict__ b1,
    const unsigned short* __restrict__ W2p,   // packed [8][8][64][8]
    const float* __restrict__ b2,
    unsigned short* __restrict__ msgout)
{
  constexpr int H1ST = 264;                  // ushort stride; 2-way bank alias only
  __shared__ unsigned short h1s[4][32 * H1ST];   // 67.6 KB

  const int tid  = threadIdx.x;
  const int wave = tid >> 6;
  const int lane = tid & 63;
  const int c    = lane & 15;
  const int quad = lane >> 4;
  const int m0   = blockIdx.x * 128 + wave * 32;

  const int mA = min(m0 + c,      NUM_M - 1);
  const int mB = min(m0 + 16 + c, NUM_M - 1);
  const int fA = first[mA],  sA = second[mA];
  const int fB = first[mB],  sB = second[mB];

  // activation B-frags for both sets
  bf16x8 actA[8], actB[8];
  {
    const unsigned short* fra = lsb + (size_t)fA * DIM + quad * 8;
    const unsigned short* sra = lsb + (size_t)sA * DIM + quad * 8;
    const unsigned short* frb = lsb + (size_t)fB * DIM + quad * 8;
    const unsigned short* srb = lsb + (size_t)sB * DIM + quad * 8;
    #pragma unroll
    for (int ks = 0; ks < 4; ++ks) {
      actA[ks]     = *(const bf16x8*)(fra + ks * 32);
      actA[4 + ks] = *(const bf16x8*)(sra + ks * 32);
      actB[ks]     = *(const bf16x8*)(frb + ks * 32);
      actB[4 + ks] = *(const bf16x8*)(srb + ks * 32);
    }
  }

  // ---- layer 1: N=256 (16 frags), K=256 (8 k-steps), 2 msg-sets ----
  f32x4 accA[16], accB[16];
  #pragma unroll
  for (int i = 0; i < 16; ++i) { accA[i] = (f32x4)(0.f); accB[i] = (f32x4)(0.f); }

  const bf16x8* W1f = (const bf16x8*)W1p;
  #pragma unroll
  for (int ks = 0; ks < 8; ++ks) {
    #pragma unroll
    for (int nf = 0; nf < 16; ++nf) {
      bf16x8 wa = W1f[(ks * 16 + nf) * 64 + lane];
      accA[nf] = MFMA(wa, actA[ks], accA[nf]);
      accB[nf] = MFMA(wa, actB[ks], accB[nf]);
    }
  }

  // epilogue 1: bias+relu -> bf16 -> LDS [row=set*16+c][n]
  #pragma unroll
  for (int nf = 0; nf < 16; ++nf) {
    int n0 = nf * 16 + quad * 4;
    float4 bv = *(const float4*)(b1 + n0);
    ushort4 pa, pb;
    pa.x = f2bf(relu_(accA[nf][0] + bv.x));
    pa.y = f2bf(relu_(accA[nf][1] + bv.y));
    pa.z = f2bf(relu_(accA[nf][2] + bv.z));
    pa.w = f2bf(relu_(accA[nf][3] + bv.w));
    pb.x = f2bf(relu_(accB[nf][0] + bv.x));
    pb.y = f2bf(relu_(accB[nf][1] + bv.y));
    pb.z = f2bf(relu_(accB[nf][2] + bv.z));
    pb.w = f2bf(relu_(accB[nf][3] + bv.w));
    *(ushort4*)&h1s[wave][(c)      * H1ST + n0] = pa;
    *(ushort4*)&h1s[wave][(16 + c) * H1ST + n0] = pb;
  }
  __builtin_amdgcn_s_waitcnt(0);             // wave-local LDS drain
  __builtin_amdgcn_wave_barrier();

  // ---- layer 2: N=128 (8 frags), K=256 (8 k-steps) ----
  f32x4 acc2A[8], acc2B[8];
  #pragma unroll
  for (int i = 0; i < 8; ++i) { acc2A[i] = (f32x4)(0.f); acc2B[i] = (f32x4)(0.f); }

  const bf16x8* W2f = (const bf16x8*)W2p;
  #pragma unroll
  for (int ks = 0; ks < 8; ++ks) {
    bf16x8 bbA = *(const bf16x8*)&h1s[wave][(c)      * H1ST + ks * 32 + quad * 8];
    bf16x8 bbB = *(const bf16x8*)&h1s[wave][(16 + c) * H1ST + ks * 32 + quad * 8];
    #pragma unroll
    for (int nf = 0; nf < 8; ++nf) {
      bf16x8 wa = W2f[(ks * 8 + nf) * 64 + lane];
      acc2A[nf] = MFMA(wa, bbA, acc2A[nf]);
      acc2B[nf] = MFMA(wa, bbB, acc2B[nf]);
    }
  }

  // epilogue 2: bias+relu -> bf16 rows (guarded plain stores)
  #pragma unroll
  for (int set = 0; set < 2; ++set) {
    int m = m0 + set * 16 + c;
    if (m >= NUM_M) continue;
    unsigned short* dst = msgout + (size_t)m * DIM;
    f32x4* a2 = set ? acc2B : acc2A;
    #pragma unroll
    for (int nf = 0; nf < 8; ++nf) {
      int n0 = nf * 16 + quad * 4;
      float4 bv = *(const float4*)(b2 + n0);
      ushort4 pk;
      pk.x = f2bf(relu_(a2[nf][0] + bv.x));
      pk.y = f2bf(relu_(a2[nf][1] + bv.y));
      pk.z = f2bf(relu_(a2[nf][2] + bv.z));
      pk.w = f2bf(relu_(a2[nf][3] + bv.w));
      *(ushort4*)(dst + n0) = pk;
    }
  }
}

// ---------------- GRU (MFMA) with fused CSR segment-sum ----------------
__global__ __launch_bounds__(256) void gru_kernel(
    const unsigned short* __restrict__ msgb,  // [M,128] bf16
    const int* __restrict__ rowptr,           // [E+1]
    const int* __restrict__ order,            // [M]
    unsigned short* __restrict__ lsb,         // h bf16, in-place
    float* __restrict__ lsf,                  // h fp32 master, in-place
    const unsigned short* __restrict__ Wzrp,  // packed [8][16][64][8]
    const unsigned short* __restrict__ Wkhp,  // packed [4][8][64][8]
    const unsigned short* __restrict__ Wrhp,  // packed [4][8][64][8]
    const float* __restrict__ gb)             // [2][384]
{
  const int tid  = threadIdx.x;
  const int wave = tid >> 6;
  const int lane = tid & 63;
  const int c    = lane & 15;
  const int quad = lane >> 4;
  const int e0   = blockIdx.x * 64 + wave * 16;
  const int e    = e0 + c;
  const int ec   = min(e, NUM_E - 1);

  // fused segment-sum: x[ec] = sum over CSR list of bf16 msg rows (fp32 acc)
  float xacc[4][8];
  #pragma unroll
  for (int ks = 0; ks < 4; ++ks)
    #pragma unroll
    for (int j = 0; j < 8; ++j) xacc[ks][j] = 0.f;

  const int rs = rowptr[ec], re = rowptr[ec + 1];
  for (int p = rs; p < re; ++p) {
    int m = order[p];
    const unsigned short* mr = msgb + (size_t)m * DIM + quad * 8;
    #pragma unroll
    for (int ks = 0; ks < 4; ++ks) {
      bf16x8 v = *(const bf16x8*)(mr + ks * 32);
      #pragma unroll
      for (int j = 0; j < 8; ++j)
        xacc[ks][j] += bf2f((unsigned short)v[j]);
    }
  }

  bf16x8 xf[4], hf[4];
  #pragma unroll
  for (int ks = 0; ks < 4; ++ks) {
    bf16x8 v;
    #pragma unroll
    for (int j = 0; j < 8; ++j) v[j] = (short)f2bf(xacc[ks][j]);
    xf[ks] = v;
  }
  const unsigned short* hrow = lsb + (size_t)ec * DIM + quad * 8;
  #pragma unroll
  for (int ks = 0; ks < 4; ++ks) hf[ks] = *(const bf16x8*)(hrow + ks * 32);

  // ---- zr gates: [x|h] @ [gk;gr][:, :256], N=256, K=256 ----
  f32x4 azr[16];
  #pragma unroll
  for (int i = 0; i < 16; ++i) azr[i] = (f32x4)(0.f);
  const bf16x8* Wzrf = (const bf16x8*)Wzrp;
  #pragma unroll
  for (int ks = 0; ks < 8; ++ks) {
    bf16x8 bb = (ks < 4) ? xf[ks] : hf[ks - 4];
    #pragma unroll
    for (int nf = 0; nf < 16; ++nf) {
      bf16x8 wa = Wzrf[(ks * 16 + nf) * 64 + lane];
      azr[nf] = MFMA(wa, bb, azr[nf]);
    }
  }

  // ---- h-gate: xh = x @ gk[:,256:], hh = h @ gr[:,256:], N=128, K=128 ----
  f32x4 axh[8], ahh[8];
  #pragma unroll
  for (int i = 0; i < 8; ++i) { axh[i] = (f32x4)(0.f); ahh[i] = (f32x4)(0.f); }
  const bf16x8* Wkhf = (const bf16x8*)Wkhp;
  const bf16x8* Wrhf = (const bf16x8*)Wrhp;
  #pragma unroll
  for (int ks = 0; ks < 4; ++ks) {
    #pragma unroll
    for (int nf = 0; nf < 8; ++nf) {
      axh[nf] = MFMA(Wkhf[(ks * 8 + nf) * 64 + lane], xf[ks], axh[nf]);
      ahh[nf] = MFMA(Wrhf[(ks * 8 + nf) * 64 + lane], hf[ks], ahh[nf]);
    }
  }

  if (e >= NUM_E) return;

  const float4* gbv = (const float4*)gb;
  #pragma unroll
  for (int nf = 0; nf < 8; ++nf) {
    int n0 = nf * 16 + quad * 4;
    int q4 = n0 >> 2;
    float4 b0z = gbv[q4],       b0r = gbv[32 + q4],  b0h = gbv[64 + q4];
    float4 b1z = gbv[96 + q4],  b1r = gbv[128 + q4], b1h = gbv[160 + q4];
    float4 hold = *(const float4*)(lsf + (size_t)e * DIM + n0);
    const float* pz  = (const float*)&azr[nf];
    const float* pr  = (const float*)&azr[nf + 8];
    const float* pxh = (const float*)&axh[nf];
    const float* phh = (const float*)&ahh[nf];
    const float* b0za = (const float*)&b0z; const float* b0ra = (const float*)&b0r;
    const float* b0ha = (const float*)&b0h; const float* b1za = (const float*)&b1z;
    const float* b1ra = (const float*)&b1r; const float* b1ha = (const float*)&b1h;
    const float* ho = (const float*)&hold;
    float outv[4];
    #pragma unroll
    for (int i = 0; i < 4; ++i) {
      float z  = sigmoidf_(pz[i] + b0za[i] + b1za[i]);
      float r  = sigmoidf_(pr[i] + b0ra[i] + b1ra[i]);
      float hc = tanhf_(pxh[i] + b0ha[i] + r * (phh[i] + b1ha[i]));
      outv[i] = z * ho[i] + (1.f - z) * hc;
    }
    *(float4*)(lsf + (size_t)e * DIM + n0) =
        make_float4(outv[0], outv[1], outv[2], outv[3]);
    ushort4 pk;
    pk.x = f2bf(outv[0]); pk.y = f2bf(outv[1]);
    pk.z = f2bf(outv[2]); pk.w = f2bf(outv[3]);
    *(ushort4*)(lsb + (size_t)e * DIM + n0) = pk;
  }
}

// ---------------- graph segment-sum (ids sorted, parallel run-wise) ----------------
// grid = ceil(NUM_E/GS_ER), block 256: lane owns dim d=tid&127, two edge strides.
__global__ __launch_bounds__(256) void graph_sum_kernel(
    const float* __restrict__ ls, const int* __restrict__ gids,
    float* __restrict__ gs) {
  const int t = threadIdx.x;
  const int d = t & 127;
  const int half = t >> 7;
  const int e0 = blockIdx.x * GS_ER;
  const int e1 = min(e0 + GS_ER, NUM_E);
  float acc = 0.f;
  int cur = -1;
  for (int e = e0 + half; e < e1; e += 2) {
    int g = gids[e];
    if (g != cur) {
      if (cur >= 0) atomicAdd(&gs[cur * DIM + d], acc);
      acc = 0.f;
      cur = g;
    }
    acc += ls[(size_t)e * DIM + d];
  }
  if (cur >= 0) atomicAdd(&gs[cur * DIM + d], acc);
}

// ---------------- readout ----------------
__global__ __launch_bounds__(256) void readout1_kernel(
    const float* __restrict__ gs, const float* __restrict__ W,
    const float* __restrict__ b, float* __restrict__ r1) {
  __shared__ float sh[DIM];
  int g = blockIdx.x, c = threadIdx.x;
  if (c < DIM) sh[c] = gs[g * DIM + c];
  __syncthreads();
  float s = b[c];
  for (int k = 0; k < DIM; ++k) s += sh[k] * W[k * HID + c];
  r1[g * HID + c] = relu_(s);
}

__global__ __launch_bounds__(256) void readout2_kernel(
    const float* __restrict__ r1, const float* __restrict__ W,
    const float* __restrict__ b, float* __restrict__ r2) {
  __shared__ float sh[HID];
  int g = blockIdx.x, c = threadIdx.x;
  sh[c] = r1[g * HID + c];
  __syncthreads();
  float s = b[c];
  for (int k = 0; k < HID; ++k) s += sh[k] * W[k * HID + c];
  r2[g * HID + c] = relu_(s);
}

__global__ void readout3_kernel(const float* __restrict__ r2,
                                const float* __restrict__ W,
                                const float* __restrict__ b,
                                float* __restrict__ out) {
  int g = threadIdx.x;
  if (g < NG) {
    float s = b[0];
    for (int k = 0; k < HID; ++k) s += r2[g * HID + k] * W[k];
    out[g] = s;
  }
}

extern "C" void kernel_launch(void* const* d_in, const int* in_sizes, int n_in,
                              void* d_out, int out_size, void* d_ws, size_t ws_size,
                              hipStream_t stream) {
  float* ls          = (float*)d_in[0];        // fp32 master h; harness restores
  const int* first   = (const int*)d_in[1];
  const int* second  = (const int*)d_in[2];
  const int* gids    = (const int*)d_in[3];
  const float* mW1   = (const float*)d_in[5];
  const float* mb1   = (const float*)d_in[6];
  const float* mW2   = (const float*)d_in[7];
  const float* mb2   = (const float*)d_in[8];
  const float* gk    = (const float*)d_in[9];
  const float* gr    = (const float*)d_in[10];
  const float* gb    = (const float*)d_in[11];
  const float* rW1   = (const float*)d_in[12];
  const float* rb1   = (const float*)d_in[13];
  const float* rW2   = (const float*)d_in[14];
  const float* rb2   = (const float*)d_in[15];
  const float* rW3   = (const float*)d_in[16];
  const float* rb3   = (const float*)d_in[17];
  float* out = (float*)d_out;

  // workspace layout
  char* w = (char*)d_ws;
  unsigned short* msgb = (unsigned short*)w;    w += (size_t)NUM_M * DIM * 2;   // 51.2 MB
  unsigned short* lsb  = (unsigned short*)w;    w += (size_t)NUM_E * DIM * 2;   // 25.6 MB
  float* gs    = (float*)w;                     w += NG * DIM * 4;
  float* r1    = (float*)w;                     w += NG * HID * 4;
  float* r2    = (float*)w;                     w += NG * HID * 4;
  int* counts  = (int*)w;                       w += NUM_E * 4;
  int* cursor  = (int*)w;                       w += NUM_E * 4;
  int* rowptr  = (int*)w;                       w += (NUM_E + 4) * 4;
  int* order   = (int*)w;                       w += NUM_M * 4;
  int* partials= (int*)w;                       w += NB_SCAN * 4;
  int* basep   = (int*)w;                       w += NB_SCAN * 4;
  unsigned short* W1p  = (unsigned short*)w;    w += 256 * 256 * 2;
  unsigned short* W2p  = (unsigned short*)w;    w += 256 * 128 * 2;
  unsigned short* Wzrp = (unsigned short*)w;    w += 256 * 256 * 2;
  unsigned short* Wkhp = (unsigned short*)w;    w += 128 * 128 * 2;
  unsigned short* Wrhp = (unsigned short*)w;    w += 128 * 128 * 2;

  // prep: bf16 link_state + packed weights
  const int n4 = NUM_E * DIM / 4;
  cvt_bf_kernel<<<(n4 + 255) / 256, 256, 0, stream>>>((const float4*)ls, (ushort4*)lsb, n4);
  pack_w_kernel<<<32, 256, 0, stream>>>(mW1, mW1, 256, 256, 256, 256, 0, W1p);
  pack_w_kernel<<<16, 256, 0, stream>>>(mW2, mW2, 256, 256, 128, 128, 0, W2p);
  pack_w_kernel<<<32, 256, 0, stream>>>(gk, gr, 128, 256, 256, 384, 0, Wzrp);
  pack_w_kernel<<<8, 256, 0, stream>>>(gk, gk, 128, 128, 128, 384, 256, Wkhp);
  pack_w_kernel<<<8, 256, 0, stream>>>(gr, gr, 128, 128, 128, 384, 256, Wrhp);

  // CSR build (counts+cursor zeroed together: 2*NUM_E ints = 50000 f4)
  zero_kernel<<<(2 * NUM_E / 4 + 255) / 256, 256, 0, stream>>>((float4*)counts, 2 * NUM_E / 4);
  hist_kernel<<<(NUM_M + 255) / 256, 256, 0, stream>>>(second, counts);
  scan1_kernel<<<NB_SCAN, 256, 0, stream>>>(counts, partials);
  scan2_kernel<<<1, 64, 0, stream>>>(partials, basep, rowptr);
  scan3_kernel<<<NB_SCAN, 256, 0, stream>>>(counts, basep, rowptr);
  scatter_kernel<<<(NUM_M + 255) / 256, 256, 0, stream>>>(second, rowptr, cursor, order);
  // zero gs accumulator (NG*DIM = 8192 floats = 2048 f4)
  zero_kernel<<<8, 256, 0, stream>>>((float4*)gs, NG * DIM / 4);

  const int msgBlocks = (NUM_M + 127) / 128;
  const int gruBlocks = (NUM_E + 63) / 64;
  for (int t = 0; t < TITER; ++t) {
    msg_kernel<<<msgBlocks, 256, 0, stream>>>(lsb, first, second, W1p, mb1, W2p, mb2, msgb);
    gru_kernel<<<gruBlocks, 256, 0, stream>>>(msgb, rowptr, order, lsb, ls, Wzrp, Wkhp, Wrhp, gb);
  }
  graph_sum_kernel<<<(NUM_E + GS_ER - 1) / GS_ER, 256, 0, stream>>>(ls, gids, gs);
  readout1_kernel<<<NG, HID, 0, stream>>>(gs, rW1, rb1, r1);
  readout2_kernel<<<NG, HID, 0, stream>>>(r1, rW2, rb2, r2);
  readout3_kernel<<<1, 64, 0, stream>>>(r2, rW3, rb3, out);
}

// Round 5
// 791.637 us; speedup vs baseline: 6.3582x; 1.2338x over previous
//
#include <hip/hip_runtime.h>

#define NUM_E 100000
#define NUM_M 200000
#define DIM   128
#define HID   256
#define NG    64
#define TITER 3
#define NB_SCAN 98   // ceil(NUM_E/1024)
#define GS_ER 128    // edges per block in graph_sum

typedef __attribute__((ext_vector_type(8))) short bf16x8;
typedef __attribute__((ext_vector_type(4))) float f32x4;

__device__ __forceinline__ unsigned short f2bf(float f) {
  unsigned u = __float_as_uint(f);
  u += 0x7FFF + ((u >> 16) & 1);          // RNE
  return (unsigned short)(u >> 16);
}
__device__ __forceinline__ float bf2f(unsigned short h) {
  return __uint_as_float(((unsigned)h) << 16);
}
__device__ __forceinline__ float sigmoidf_(float v) {
  return 1.f / (1.f + __expf(-v));
}
__device__ __forceinline__ float tanhf_(float u) {
  u = fminf(fmaxf(u, -15.f), 15.f);
  float ex = __expf(-2.f * u);
  return (1.f - ex) / (1.f + ex);
}
__device__ __forceinline__ float relu_(float v) { return fmaxf(v, 0.f); }

#define MFMA(a, b, c) __builtin_amdgcn_mfma_f32_16x16x32_bf16((a), (b), (c), 0, 0, 0)

// ---------------- zero ----------------
__global__ void zero_kernel(float4* __restrict__ p, int n4) {
  int i = blockIdx.x * blockDim.x + threadIdx.x;
  if (i < n4) p[i] = make_float4(0.f, 0.f, 0.f, 0.f);
}

// ---------------- fp32 -> bf16 bulk convert ----------------
__global__ void cvt_bf_kernel(const float4* __restrict__ src,
                              ushort4* __restrict__ dst, int n4) {
  int i = blockIdx.x * blockDim.x + threadIdx.x;
  if (i < n4) {
    float4 v = src[i];
    ushort4 o;
    o.x = f2bf(v.x); o.y = f2bf(v.y); o.z = f2bf(v.z); o.w = f2bf(v.w);
    dst[i] = o;
  }
}

// ---------------- CSR build: histogram / scan / scatter ----------------
__global__ void hist_kernel(const int* __restrict__ second, int* __restrict__ counts) {
  int m = blockIdx.x * blockDim.x + threadIdx.x;
  if (m < NUM_M) atomicAdd(&counts[second[m]], 1);
}

// block scan over 1024-elem chunks (256 thr x 4)
__global__ __launch_bounds__(256) void scan1_kernel(const int* __restrict__ counts,
                                                    int* __restrict__ partials) {
  __shared__ int sh[256];
  int b = blockIdx.x, t = threadIdx.x;
  int i0 = b * 1024 + t * 4;
  int c0 = (i0 + 0 < NUM_E) ? counts[i0 + 0] : 0;
  int c1 = (i0 + 1 < NUM_E) ? counts[i0 + 1] : 0;
  int c2 = (i0 + 2 < NUM_E) ? counts[i0 + 2] : 0;
  int c3 = (i0 + 3 < NUM_E) ? counts[i0 + 3] : 0;
  int tsum = c0 + c1 + c2 + c3;
  sh[t] = tsum;
  __syncthreads();
  for (int off = 1; off < 256; off <<= 1) {
    int v = (t >= off) ? sh[t - off] : 0;
    __syncthreads();
    sh[t] += v;
    __syncthreads();
  }
  if (t == 255) partials[b] = sh[255];
}

__global__ void scan2_kernel(const int* __restrict__ partials, int* __restrict__ base,
                             int* __restrict__ rowptr) {
  if (threadIdx.x == 0) {
    int run = 0;
    for (int b = 0; b < NB_SCAN; ++b) { base[b] = run; run += partials[b]; }
    rowptr[NUM_E] = NUM_M;
  }
}

__global__ __launch_bounds__(256) void scan3_kernel(const int* __restrict__ counts,
                                                    const int* __restrict__ base,
                                                    int* __restrict__ rowptr) {
  __shared__ int sh[256];
  int b = blockIdx.x, t = threadIdx.x;
  int i0 = b * 1024 + t * 4;
  int c0 = (i0 + 0 < NUM_E) ? counts[i0 + 0] : 0;
  int c1 = (i0 + 1 < NUM_E) ? counts[i0 + 1] : 0;
  int c2 = (i0 + 2 < NUM_E) ? counts[i0 + 2] : 0;
  int c3 = (i0 + 3 < NUM_E) ? counts[i0 + 3] : 0;
  int tsum = c0 + c1 + c2 + c3;
  sh[t] = tsum;
  __syncthreads();
  for (int off = 1; off < 256; off <<= 1) {
    int v = (t >= off) ? sh[t - off] : 0;
    __syncthreads();
    sh[t] += v;
    __syncthreads();
  }
  int p = base[b] + (sh[t] - tsum);
  if (i0 + 0 < NUM_E) rowptr[i0 + 0] = p;
  if (i0 + 1 < NUM_E) rowptr[i0 + 1] = p + c0;
  if (i0 + 2 < NUM_E) rowptr[i0 + 2] = p + c0 + c1;
  if (i0 + 3 < NUM_E) rowptr[i0 + 3] = p + c0 + c1 + c2;
}

__global__ void scatter_kernel(const int* __restrict__ second,
                               const int* __restrict__ rowptr,
                               int* __restrict__ cursor, int* __restrict__ order) {
  int m = blockIdx.x * blockDim.x + threadIdx.x;
  if (m < NUM_M) {
    int e = second[m];
    int pos = atomicAdd(&cursor[e], 1);
    int idx = rowptr[e] + pos;
    if (idx < rowptr[e + 1]) order[idx] = m;   // guard: rocprof replay re-runs w/o re-zero
  }
}

// ---------------- weight pack into MFMA A-fragment order ----------------
__global__ void pack_w_kernel(const float* __restrict__ srcA,
                              const float* __restrict__ srcB, int KrowsA,
                              int K, int N, int src_ld, int col_off,
                              unsigned short* __restrict__ dst) {
  int idx = blockIdx.x * blockDim.x + threadIdx.x;   // one 8-elem chunk per thread
  int total = (K / 32) * (N / 16) * 64;
  if (idx >= total) return;
  int l = idx & 63;
  int t = idx >> 6;
  int NF = N / 16;
  int nf = t % NF;
  int ks = t / NF;
  int n = nf * 16 + (l & 15) + col_off;
  int k0 = ks * 32 + (l >> 4) * 8;
  unsigned short o[8];
  #pragma unroll
  for (int j = 0; j < 8; ++j) {
    int k = k0 + j;
    const float* src = (k < KrowsA) ? (srcA + (size_t)k * src_ld)
                                    : (srcB + (size_t)(k - KrowsA) * src_ld);
    o[j] = f2bf(src[n]);
  }
  ushort4* d = (ushort4*)(dst + (size_t)idx * 8);
  d[0] = make_ushort4(o[0], o[1], o[2], o[3]);
  d[1] = make_ushort4(o[4], o[5], o[6], o[7]);
}

// ---------------- message MLP (MFMA), permuted output, no atomics ----------------
// Processes message order[idx], writes result to physical row idx -> edge e's
// messages occupy contiguous rows rowptr[e]..rowptr[e+1] of msgout.
__global__ __launch_bounds__(256, 2) void msg_kernel(
    const unsigned short* __restrict__ lsb,   // [E,128] bf16
    const int* __restrict__ first, const int* __restrict__ second,
    const int* __restrict__ order,            // [M] permutation
    const unsigned short* __restrict__ W1p,   // packed [8][16][64][8]
    const float* __restrict__ b1,
    const unsigned short* __restrict__ W2p,   // packed [8][8][64][8]
    const float* __restrict__ b2,
    unsigned short* __restrict__ msgout)
{
  constexpr int H1ST = 264;                  // ushort stride; 2-way bank alias only
  __shared__ unsigned short h1s[4][32 * H1ST];   // 67.6 KB

  const int tid  = threadIdx.x;
  const int wave = tid >> 6;
  const int lane = tid & 63;
  const int c    = lane & 15;
  const int quad = lane >> 4;
  const int m0   = blockIdx.x * 128 + wave * 32;

  const int iA = min(m0 + c,      NUM_M - 1);
  const int iB = min(m0 + 16 + c, NUM_M - 1);
  const int mA = order[iA], mB = order[iB];
  const int fA = first[mA],  sA = second[mA];
  const int fB = first[mB],  sB = second[mB];

  // activation B-frags for both sets
  bf16x8 actA[8], actB[8];
  {
    const unsigned short* fra = lsb + (size_t)fA * DIM + quad * 8;
    const unsigned short* sra = lsb + (size_t)sA * DIM + quad * 8;
    const unsigned short* frb = lsb + (size_t)fB * DIM + quad * 8;
    const unsigned short* srb = lsb + (size_t)sB * DIM + quad * 8;
    #pragma unroll
    for (int ks = 0; ks < 4; ++ks) {
      actA[ks]     = *(const bf16x8*)(fra + ks * 32);
      actA[4 + ks] = *(const bf16x8*)(sra + ks * 32);
      actB[ks]     = *(const bf16x8*)(frb + ks * 32);
      actB[4 + ks] = *(const bf16x8*)(srb + ks * 32);
    }
  }

  // ---- layer 1: N=256 (16 frags), K=256 (8 k-steps), 2 msg-sets ----
  f32x4 accA[16], accB[16];
  #pragma unroll
  for (int i = 0; i < 16; ++i) { accA[i] = (f32x4)(0.f); accB[i] = (f32x4)(0.f); }

  const bf16x8* W1f = (const bf16x8*)W1p;
  #pragma unroll
  for (int ks = 0; ks < 8; ++ks) {
    #pragma unroll
    for (int nf = 0; nf < 16; ++nf) {
      bf16x8 wa = W1f[(ks * 16 + nf) * 64 + lane];
      accA[nf] = MFMA(wa, actA[ks], accA[nf]);
      accB[nf] = MFMA(wa, actB[ks], accB[nf]);
    }
  }

  // epilogue 1: bias+relu -> bf16 -> LDS [row=set*16+c][n]
  #pragma unroll
  for (int nf = 0; nf < 16; ++nf) {
    int n0 = nf * 16 + quad * 4;
    float4 bv = *(const float4*)(b1 + n0);
    ushort4 pa, pb;
    pa.x = f2bf(relu_(accA[nf][0] + bv.x));
    pa.y = f2bf(relu_(accA[nf][1] + bv.y));
    pa.z = f2bf(relu_(accA[nf][2] + bv.z));
    pa.w = f2bf(relu_(accA[nf][3] + bv.w));
    pb.x = f2bf(relu_(accB[nf][0] + bv.x));
    pb.y = f2bf(relu_(accB[nf][1] + bv.y));
    pb.z = f2bf(relu_(accB[nf][2] + bv.z));
    pb.w = f2bf(relu_(accB[nf][3] + bv.w));
    *(ushort4*)&h1s[wave][(c)      * H1ST + n0] = pa;
    *(ushort4*)&h1s[wave][(16 + c) * H1ST + n0] = pb;
  }
  __builtin_amdgcn_s_waitcnt(0);             // wave-local LDS drain
  __builtin_amdgcn_wave_barrier();

  // ---- layer 2: N=128 (8 frags), K=256 (8 k-steps) ----
  f32x4 acc2A[8], acc2B[8];
  #pragma unroll
  for (int i = 0; i < 8; ++i) { acc2A[i] = (f32x4)(0.f); acc2B[i] = (f32x4)(0.f); }

  const bf16x8* W2f = (const bf16x8*)W2p;
  #pragma unroll
  for (int ks = 0; ks < 8; ++ks) {
    bf16x8 bbA = *(const bf16x8*)&h1s[wave][(c)      * H1ST + ks * 32 + quad * 8];
    bf16x8 bbB = *(const bf16x8*)&h1s[wave][(16 + c) * H1ST + ks * 32 + quad * 8];
    #pragma unroll
    for (int nf = 0; nf < 8; ++nf) {
      bf16x8 wa = W2f[(ks * 8 + nf) * 64 + lane];
      acc2A[nf] = MFMA(wa, bbA, acc2A[nf]);
      acc2B[nf] = MFMA(wa, bbB, acc2B[nf]);
    }
  }

  // epilogue 2: bias+relu -> bf16 rows at PHYSICAL index (permuted layout)
  #pragma unroll
  for (int set = 0; set < 2; ++set) {
    int idx = m0 + set * 16 + c;
    if (idx >= NUM_M) continue;
    unsigned short* dst = msgout + (size_t)idx * DIM;
    f32x4* a2 = set ? acc2B : acc2A;
    #pragma unroll
    for (int nf = 0; nf < 8; ++nf) {
      int n0 = nf * 16 + quad * 4;
      float4 bv = *(const float4*)(b2 + n0);
      ushort4 pk;
      pk.x = f2bf(relu_(a2[nf][0] + bv.x));
      pk.y = f2bf(relu_(a2[nf][1] + bv.y));
      pk.z = f2bf(relu_(a2[nf][2] + bv.z));
      pk.w = f2bf(relu_(a2[nf][3] + bv.w));
      *(ushort4*)(dst + n0) = pk;
    }
  }
}

// ---------------- GRU (MFMA), contiguous CSR sum, per-column accumulation ----------------
__global__ __launch_bounds__(256) void gru_kernel(
    const unsigned short* __restrict__ msgb,  // [M,128] bf16, permuted (CSR row order)
    const int* __restrict__ rowptr,           // [E+1]
    unsigned short* __restrict__ lsb,         // h bf16, in-place
    float* __restrict__ lsf,                  // h fp32 master, in-place
    const unsigned short* __restrict__ Wzrp,  // packed [8][16][64][8]
    const unsigned short* __restrict__ Wkhp,  // packed [4][8][64][8]
    const unsigned short* __restrict__ Wrhp,  // packed [4][8][64][8]
    const float* __restrict__ gb)             // [2][384]
{
  const int tid  = threadIdx.x;
  const int wave = tid >> 6;
  const int lane = tid & 63;
  const int c    = lane & 15;
  const int quad = lane >> 4;
  const int e0   = blockIdx.x * 64 + wave * 16;
  const int e    = e0 + c;
  const int ec   = min(e, NUM_E - 1);

  // fused segment-sum: rows rowptr[ec]..rowptr[ec+1] are CONTIGUOUS in msgb
  float xacc[4][8];
  #pragma unroll
  for (int ks = 0; ks < 4; ++ks)
    #pragma unroll
    for (int j = 0; j < 8; ++j) xacc[ks][j] = 0.f;

  const int rs = rowptr[ec], re = rowptr[ec + 1];
  for (int p = rs; p < re; ++p) {
    const unsigned short* mr = msgb + (size_t)p * DIM + quad * 8;
    #pragma unroll
    for (int ks = 0; ks < 4; ++ks) {
      bf16x8 v = *(const bf16x8*)(mr + ks * 32);
      #pragma unroll
      for (int j = 0; j < 8; ++j)
        xacc[ks][j] += bf2f((unsigned short)v[j]);
    }
  }

  bf16x8 xf[4], hf[4];
  #pragma unroll
  for (int ks = 0; ks < 4; ++ks) {
    bf16x8 v;
    #pragma unroll
    for (int j = 0; j < 8; ++j) v[j] = (short)f2bf(xacc[ks][j]);
    xf[ks] = v;
  }
  const unsigned short* hrow = lsb + (size_t)ec * DIM + quad * 8;
  #pragma unroll
  for (int ks = 0; ks < 4; ++ks) hf[ks] = *(const bf16x8*)(hrow + ks * 32);

  const bf16x8* Wzrf = (const bf16x8*)Wzrp;
  const bf16x8* Wkhf = (const bf16x8*)Wkhp;
  const bf16x8* Wrhf = (const bf16x8*)Wrhp;
  const float4* gbv  = (const float4*)gb;

  // per n-column: only 4 live accumulators -> low VGPR, high occupancy
  #pragma unroll 1
  for (int nf = 0; nf < 8; ++nf) {
    f32x4 az = (f32x4)(0.f), ar = (f32x4)(0.f);
    f32x4 axh = (f32x4)(0.f), ahh = (f32x4)(0.f);
    #pragma unroll
    for (int ks = 0; ks < 8; ++ks) {
      bf16x8 bb = (ks < 4) ? xf[ks] : hf[ks - 4];
      az = MFMA(Wzrf[(ks * 16 + nf) * 64 + lane], bb, az);
      ar = MFMA(Wzrf[(ks * 16 + nf + 8) * 64 + lane], bb, ar);
    }
    #pragma unroll
    for (int ks = 0; ks < 4; ++ks) {
      axh = MFMA(Wkhf[(ks * 8 + nf) * 64 + lane], xf[ks], axh);
      ahh = MFMA(Wrhf[(ks * 8 + nf) * 64 + lane], hf[ks], ahh);
    }

    if (e < NUM_E) {
      int n0 = nf * 16 + quad * 4;
      int q4 = nf * 4 + quad;
      float4 b0z = gbv[q4],       b0r = gbv[32 + q4],  b0h = gbv[64 + q4];
      float4 b1z = gbv[96 + q4],  b1r = gbv[128 + q4], b1h = gbv[160 + q4];
      float4 hold = *(const float4*)(lsf + (size_t)e * DIM + n0);
      const float* b0za = (const float*)&b0z; const float* b0ra = (const float*)&b0r;
      const float* b0ha = (const float*)&b0h; const float* b1za = (const float*)&b1z;
      const float* b1ra = (const float*)&b1r; const float* b1ha = (const float*)&b1h;
      const float* ho = (const float*)&hold;
      float outv[4];
      #pragma unroll
      for (int i = 0; i < 4; ++i) {
        float z  = sigmoidf_(az[i] + b0za[i] + b1za[i]);
        float r  = sigmoidf_(ar[i] + b0ra[i] + b1ra[i]);
        float hc = tanhf_(axh[i] + b0ha[i] + r * (ahh[i] + b1ha[i]));
        outv[i] = z * ho[i] + (1.f - z) * hc;
      }
      *(float4*)(lsf + (size_t)e * DIM + n0) =
          make_float4(outv[0], outv[1], outv[2], outv[3]);
      ushort4 pk;
      pk.x = f2bf(outv[0]); pk.y = f2bf(outv[1]);
      pk.z = f2bf(outv[2]); pk.w = f2bf(outv[3]);
      *(ushort4*)(lsb + (size_t)e * DIM + n0) = pk;
    }
  }
}

// ---------------- graph segment-sum (ids sorted, parallel run-wise) ----------------
__global__ __launch_bounds__(256) void graph_sum_kernel(
    const float* __restrict__ ls, const int* __restrict__ gids,
    float* __restrict__ gs) {
  const int t = threadIdx.x;
  const int d = t & 127;
  const int half = t >> 7;
  const int e0 = blockIdx.x * GS_ER;
  const int e1 = min(e0 + GS_ER, NUM_E);
  float acc = 0.f;
  int cur = -1;
  for (int e = e0 + half; e < e1; e += 2) {
    int g = gids[e];
    if (g != cur) {
      if (cur >= 0) atomicAdd(&gs[cur * DIM + d], acc);
      acc = 0.f;
      cur = g;
    }
    acc += ls[(size_t)e * DIM + d];
  }
  if (cur >= 0) atomicAdd(&gs[cur * DIM + d], acc);
}

// ---------------- readout ----------------
__global__ __launch_bounds__(256) void readout1_kernel(
    const float* __restrict__ gs, const float* __restrict__ W,
    const float* __restrict__ b, float* __restrict__ r1) {
  __shared__ float sh[DIM];
  int g = blockIdx.x, c = threadIdx.x;
  if (c < DIM) sh[c] = gs[g * DIM + c];
  __syncthreads();
  float s = b[c];
  for (int k = 0; k < DIM; ++k) s += sh[k] * W[k * HID + c];
  r1[g * HID + c] = relu_(s);
}

__global__ __launch_bounds__(256) void readout2_kernel(
    const float* __restrict__ r1, const float* __restrict__ W,
    const float* __restrict__ b, float* __restrict__ r2) {
  __shared__ float sh[HID];
  int g = blockIdx.x, c = threadIdx.x;
  sh[c] = r1[g * HID + c];
  __syncthreads();
  float s = b[c];
  for (int k = 0; k < HID; ++k) s += sh[k] * W[k * HID + c];
  r2[g * HID + c] = relu_(s);
}

__global__ void readout3_kernel(const float* __restrict__ r2,
                                const float* __restrict__ W,
                                const float* __restrict__ b,
                                float* __restrict__ out) {
  int g = threadIdx.x;
  if (g < NG) {
    float s = b[0];
    for (int k = 0; k < HID; ++k) s += r2[g * HID + k] * W[k];
    out[g] = s;
  }
}

extern "C" void kernel_launch(void* const* d_in, const int* in_sizes, int n_in,
                              void* d_out, int out_size, void* d_ws, size_t ws_size,
                              hipStream_t stream) {
  float* ls          = (float*)d_in[0];        // fp32 master h; harness restores
  const int* first   = (const int*)d_in[1];
  const int* second  = (const int*)d_in[2];
  const int* gids    = (const int*)d_in[3];
  const float* mW1   = (const float*)d_in[5];
  const float* mb1   = (const float*)d_in[6];
  const float* mW2   = (const float*)d_in[7];
  const float* mb2   = (const float*)d_in[8];
  const float* gk    = (const float*)d_in[9];
  const float* gr    = (const float*)d_in[10];
  const float* gb    = (const float*)d_in[11];
  const float* rW1   = (const float*)d_in[12];
  const float* rb1   = (const float*)d_in[13];
  const float* rW2   = (const float*)d_in[14];
  const float* rb2   = (const float*)d_in[15];
  const float* rW3   = (const float*)d_in[16];
  const float* rb3   = (const float*)d_in[17];
  float* out = (float*)d_out;

  // workspace layout
  char* w = (char*)d_ws;
  unsigned short* msgb = (unsigned short*)w;    w += (size_t)NUM_M * DIM * 2;   // 51.2 MB
  unsigned short* lsb  = (unsigned short*)w;    w += (size_t)NUM_E * DIM * 2;   // 25.6 MB
  float* gs    = (float*)w;                     w += NG * DIM * 4;
  float* r1    = (float*)w;                     w += NG * HID * 4;
  float* r2    = (float*)w;                     w += NG * HID * 4;
  int* counts  = (int*)w;                       w += NUM_E * 4;
  int* cursor  = (int*)w;                       w += NUM_E * 4;
  int* rowptr  = (int*)w;                       w += (NUM_E + 4) * 4;
  int* order   = (int*)w;                       w += NUM_M * 4;
  int* partials= (int*)w;                       w += NB_SCAN * 4;
  int* basep   = (int*)w;                       w += NB_SCAN * 4;
  unsigned short* W1p  = (unsigned short*)w;    w += 256 * 256 * 2;
  unsigned short* W2p  = (unsigned short*)w;    w += 256 * 128 * 2;
  unsigned short* Wzrp = (unsigned short*)w;    w += 256 * 256 * 2;
  unsigned short* Wkhp = (unsigned short*)w;    w += 128 * 128 * 2;
  unsigned short* Wrhp = (unsigned short*)w;    w += 128 * 128 * 2;

  // prep: bf16 link_state + packed weights
  const int n4 = NUM_E * DIM / 4;
  cvt_bf_kernel<<<(n4 + 255) / 256, 256, 0, stream>>>((const float4*)ls, (ushort4*)lsb, n4);
  pack_w_kernel<<<32, 256, 0, stream>>>(mW1, mW1, 256, 256, 256, 256, 0, W1p);
  pack_w_kernel<<<16, 256, 0, stream>>>(mW2, mW2, 256, 256, 128, 128, 0, W2p);
  pack_w_kernel<<<32, 256, 0, stream>>>(gk, gr, 128, 256, 256, 384, 0, Wzrp);
  pack_w_kernel<<<8, 256, 0, stream>>>(gk, gk, 128, 128, 128, 384, 256, Wkhp);
  pack_w_kernel<<<8, 256, 0, stream>>>(gr, gr, 128, 128, 128, 384, 256, Wrhp);

  // CSR build (counts+cursor zeroed together: 2*NUM_E ints = 50000 f4)
  zero_kernel<<<(2 * NUM_E / 4 + 255) / 256, 256, 0, stream>>>((float4*)counts, 2 * NUM_E / 4);
  hist_kernel<<<(NUM_M + 255) / 256, 256, 0, stream>>>(second, counts);
  scan1_kernel<<<NB_SCAN, 256, 0, stream>>>(counts, partials);
  scan2_kernel<<<1, 64, 0, stream>>>(partials, basep, rowptr);
  scan3_kernel<<<NB_SCAN, 256, 0, stream>>>(counts, basep, rowptr);
  scatter_kernel<<<(NUM_M + 255) / 256, 256, 0, stream>>>(second, rowptr, cursor, order);
  // zero gs accumulator (NG*DIM = 8192 floats = 2048 f4)
  zero_kernel<<<8, 256, 0, stream>>>((float4*)gs, NG * DIM / 4);

  const int msgBlocks = (NUM_M + 127) / 128;
  const int gruBlocks = (NUM_E + 63) / 64;
  for (int t = 0; t < TITER; ++t) {
    msg_kernel<<<msgBlocks, 256, 0, stream>>>(lsb, first, second, order, W1p, mb1, W2p, mb2, msgb);
    gru_kernel<<<gruBlocks, 256, 0, stream>>>(msgb, rowptr, lsb, ls, Wzrp, Wkhp, Wrhp, gb);
  }
  graph_sum_kernel<<<(NUM_E + GS_ER - 1) / GS_ER, 256, 0, stream>>>(ls, gids, gs);
  readout1_kernel<<<NG, HID, 0, stream>>>(gs, rW1, rb1, r1);
  readout2_kernel<<<NG, HID, 0, stream>>>(r1, rW2, rb2, r2);
  readout3_kernel<<<1, 64, 0, stream>>>(r2, rW3, rb3, out);
}